// Round 4
// baseline (619.442 us; speedup 1.0000x reference)
//
#include <hip/hip_runtime.h>
#include <math.h>

// ---------------- problem constants ----------------
#define EMBED 1024
#define SLEN  2048
#define BATCH 2
#define HEADS 16
#define HD    64
#define FFN_D 4096
#define MROWS (BATCH*SLEN)   // 4096

typedef short bh8  __attribute__((ext_vector_type(8)));   // 8 bf16 in 4 VGPRs
typedef float f32x4 __attribute__((ext_vector_type(4)));

#define MFMA16(a,b,c) __builtin_amdgcn_mfma_f32_16x16x32_bf16((a),(b),(c),0,0,0)
#define GLDS16(g,l) __builtin_amdgcn_global_load_lds( \
    (__attribute__((address_space(1))) void*)(g), \
    (__attribute__((address_space(3))) void*)(l), 16, 0, 0)

__device__ inline float b2f(short s) {
  union { unsigned u; float f; } c; c.u = ((unsigned)(unsigned short)s) << 16; return c.f;
}
__device__ inline short f2b(float f) {
  union { float f; unsigned u; } c; c.f = f;
  unsigned r = (c.u + 0x7FFFu + ((c.u >> 16) & 1u)) >> 16;   // RNE
  return (short)r;
}

// ---------------- weight transpose: fp32 (K,N) -> bf16 (N,K) ----------------
__global__ __launch_bounds__(256) void transpose_w(const float* __restrict__ in,
                                                   short* __restrict__ out,
                                                   int K, int N) {
  __shared__ short sm[64][65];
  const int tid = threadIdx.x;
  const int k0 = blockIdx.y * 64, n0 = blockIdx.x * 64;
#pragma unroll
  for (int it = 0; it < 16; ++it) {
    int idx = it * 256 + tid;
    int r = idx >> 6, c = idx & 63;
    sm[r][c] = f2b(in[(size_t)(k0 + r) * N + n0 + c]);
  }
  __syncthreads();
#pragma unroll
  for (int it = 0; it < 16; ++it) {
    int idx = it * 256 + tid;
    int r = idx >> 6, c = idx & 63;
    out[(size_t)(n0 + r) * K + k0 + c] = sm[c][r];
  }
}

// ---------------- V transpose: Vb[(b*S+s)*E + h*64 + d] -> VT[(bh*64+d)*S + s] ----
__global__ __launch_bounds__(256) void transpose_v(const short* __restrict__ in,
                                                   short* __restrict__ out) {
  __shared__ short sm[64][65];
  const int tid = threadIdx.x;
  const int s0 = blockIdx.x * 64, bh = blockIdx.y;
  const int b = bh >> 4, h = bh & 15;
#pragma unroll
  for (int it = 0; it < 16; ++it) {
    int idx = it * 256 + tid;
    int r = idx >> 6, c = idx & 63;     // r: s offset, c: d
    sm[r][c] = in[((size_t)(b*SLEN + s0 + r))*EMBED + h*HD + c];
  }
  __syncthreads();
#pragma unroll
  for (int it = 0; it < 16; ++it) {
    int idx = it * 256 + tid;
    int r = idx >> 6, c = idx & 63;     // r: d, c: s offset
    out[((size_t)(bh*HD + r))*SLEN + s0 + c] = sm[c][r];
  }
}

// ---------------- layernorm: one block per row (1024 cols) ----------------
__global__ __launch_bounds__(256) void ln_kernel(const float* __restrict__ inF,
                                                 const short* __restrict__ inB,
                                                 const float* __restrict__ gw,
                                                 const float* __restrict__ bw,
                                                 short* __restrict__ out) {
  const int row = blockIdx.x, tid = threadIdx.x;
  const int w = tid >> 6;
  const size_t base = (size_t)row * EMBED;
  float x[4];
#pragma unroll
  for (int i = 0; i < 4; ++i) {
    int c = tid + i * 256;
    x[i] = inF ? inF[base + c] : b2f(inB[base + c]);
  }
  float s = x[0] + x[1] + x[2] + x[3];
  float ss = x[0]*x[0] + x[1]*x[1] + x[2]*x[2] + x[3]*x[3];
#pragma unroll
  for (int off = 32; off >= 1; off >>= 1) { s += __shfl_xor(s, off); ss += __shfl_xor(ss, off); }
  __shared__ float red[8];
  if ((tid & 63) == 0) { red[w*2] = s; red[w*2+1] = ss; }
  __syncthreads();
  s  = red[0] + red[2] + red[4] + red[6];
  ss = red[1] + red[3] + red[5] + red[7];
  const float mu = s * (1.0f/EMBED);
  const float var = ss * (1.0f/EMBED) - mu*mu;
  const float rstd = rsqrtf(var + 1e-5f);
#pragma unroll
  for (int i = 0; i < 4; ++i) {
    int c = tid + i * 256;
    out[base + c] = f2b((x[i]-mu)*rstd*gw[c] + bw[c]);
  }
}

// ---------------- RoPE in-place on Q,K ----------------
__global__ __launch_bounds__(256) void rope_kernel(short* __restrict__ Qb, short* __restrict__ Kb,
                                                   const float* __restrict__ cosb,
                                                   const float* __restrict__ sinb) {
  const int idx = blockIdx.x * 256 + threadIdx.x;      // < 2M
  const int d = idx & 31;
  const int h = (idx >> 5) & 15;
  const int s = (idx >> 9) & 2047;
  const int b = idx >> 20;
  const size_t base = ((size_t)(b*SLEN + s))*EMBED + h*HD;
  const float c0 = cosb[s*HD + d],      s0 = sinb[s*HD + d];
  const float c1 = cosb[s*HD + 32 + d], s1 = sinb[s*HD + 32 + d];
  float q0 = b2f(Qb[base + d]), q1 = b2f(Qb[base + 32 + d]);
  Qb[base + d]      = f2b(q0*c0 - q1*s0);
  Qb[base + 32 + d] = f2b(q1*c1 + q0*s1);
  float k0 = b2f(Kb[base + d]), k1 = b2f(Kb[base + 32 + d]);
  Kb[base + d]      = f2b(k0*c0 - k1*s0);
  Kb[base + 32 + d] = f2b(k1*c1 + k0*s1);
}

// ---------------- epilogue seed: out = bias[col] + resid (fp32, float4) ----------
// rows x 1024 cols; grid = rows*1024/4/256 blocks
__global__ __launch_bounds__(256) void init_out(const float* __restrict__ bias,
                                                const float* __restrict__ resid,
                                                float* __restrict__ out) {
  const int idx = blockIdx.x * 256 + threadIdx.x;      // float4 index
  f32x4 r = ((const f32x4*)resid)[idx];
  const int c = (idx << 2) & 1023;
  r[0] += bias[c]; r[1] += bias[c+1]; r[2] += bias[c+2]; r[3] += bias[c+3];
  ((f32x4*)out)[idx] = r;
}

// ---------------- MFMA GEMM: 256x256 tile, 8 waves, BK=32, depth-2 pipeline ------
// Structure change (r3 post-mortem): 128x128/4-wave hit its documented ~340 TF
// regime; 256x256/8-wave doubles MFMA per overhead unit (32 MFMA per
// {12 ds_read + 4 GLDS + 1 barrier} per wave) and gives 2 waves/SIMD of
// intra-block overlap. Pipeline (unchanged from r3, verified): triple-buffered
// LDS (96 KB, 1 block/CU), tile t staged at t-2, counted s_waitcnt vmcnt(4)
// + raw s_barrier (no vmcnt drain) so next tile's 4 loads span the barrier.
// LDS swizzle (verified 4.19M -> 0 conflicts): 16B slot s at row r holds
// global slot s ^ ((r>>1)&3); pre-swizzled global source (linear GLDS dest)
// + same XOR on ds_read offsets (rule #21: both sides).
// Wave layout: 8 waves = 2(M) x 4(N); per-wave output 128x64 = acc[8][4].
// qkv=1: N=3072, route cols to outB0/1/2 (+bias0/1/2).
// kChunk>0: split-K; atomicAdd fp32 partials into pre-seeded outF.
__global__ __launch_bounds__(512, 2) void gemm_bt(const short* __restrict__ A,
                                                  const short* __restrict__ Bt,
                                                  const float* __restrict__ bias0,
                                                  const float* __restrict__ bias1,
                                                  const float* __restrict__ bias2,
                                                  float* __restrict__ outF,
                                                  short* __restrict__ outB0,
                                                  short* __restrict__ outB1,
                                                  short* __restrict__ outB2,
                                                  const float* __restrict__ residF,
                                                  const short* __restrict__ residB,
                                                  int N, int K, int gelu, int qkv,
                                                  int kChunk) {
  __shared__ short As[3][256*32];
  __shared__ short Bs[3][256*32];
  const int tid = threadIdx.x;
  const int w = tid >> 6, L = tid & 63;
  const int quad = L >> 4, l16 = L & 15;
  const int bm = blockIdx.y * 256, bn = blockIdx.x * 256;
  const int wr = w >> 2, wc = w & 3;          // 2 x 4 wave grid
  const int wm = wr * 128, wn = wc * 64;      // per-wave 128x64 output
  const int kS = kChunk ? (int)blockIdx.z * kChunk : 0;
  const int kE = kChunk ? kS + kChunk : K;

  f32x4 acc[8][4];
#pragma unroll
  for (int i = 0; i < 8; ++i)
#pragma unroll
    for (int j = 0; j < 4; ++j) acc[i][j] = (f32x4){0.f,0.f,0.f,0.f};

  // staging: 1024 16B-chunks per matrix per tile; thread stages chunks
  // c = w*64+L and c = 512+w*64+L. LDS gets chunk c at linear slot c;
  // global source slot is (c&3) ^ ((row>>1)&3) so swizzled reads see
  // logical data (row = c>>2, 4 chunks per 64B row).
  const int c0 = w*64 + L, c1 = 512 + w*64 + L;
  const int r0c = c0 >> 2, s0c = (c0 & 3) ^ ((r0c >> 1) & 3);
  const int r1c = c1 >> 2, s1c = (c1 & 3) ^ ((r1c >> 1) & 3);
  const short* a0p = A  + (size_t)(bm + r0c)*K + s0c*8;
  const short* a1p = A  + (size_t)(bm + r1c)*K + s1c*8;
  const short* b0p = Bt + (size_t)(bn + r0c)*K + s0c*8;
  const short* b1p = Bt + (size_t)(bn + r1c)*K + s1c*8;

  // loop-invariant swizzled read offsets (shorts)
  int aoff[8], boff[4];
#pragma unroll
  for (int mi = 0; mi < 8; ++mi) {
    const int R = wm + mi*16 + l16;
    aoff[mi] = R*32 + ((quad ^ ((R >> 1) & 3))*8);
  }
#pragma unroll
  for (int ni = 0; ni < 4; ++ni) {
    const int R = wn + ni*16 + l16;
    boff[ni] = R*32 + ((quad ^ ((R >> 1) & 3))*8);
  }

#define STAGE(buf, k0) do { \
    GLDS16(a0p + (k0), &As[buf][w*512]); \
    GLDS16(a1p + (k0), &As[buf][4096 + w*512]); \
    GLDS16(b0p + (k0), &Bs[buf][w*512]); \
    GLDS16(b1p + (k0), &Bs[buf][4096 + w*512]); \
  } while (0)

  const int nt = (kE - kS) >> 5;          // >= 8 for all call sites
  STAGE(0, kS);
  STAGE(1, kS + 32);                      // 8 loads in flight
  int cur = 0;
  for (int t = 0; t < nt; ++t) {
    // wait for tile t's 4 loads (oldest); keep tile t+1's 4 in flight
    if (t + 1 < nt) asm volatile("s_waitcnt vmcnt(4)" ::: "memory");
    else            asm volatile("s_waitcnt vmcnt(0)" ::: "memory");
    __builtin_amdgcn_s_barrier();         // raw: no vmcnt drain
    asm volatile("" ::: "memory");        // fence: no LDS reads above barrier
    if (t + 2 < nt) {
      const int nb = cur ? cur - 1 : 2;   // (cur+2)%3
      STAGE(nb, kS + (t + 2)*32);
    }
    bh8 bf[4], af[4];
#pragma unroll
    for (int ni = 0; ni < 4; ++ni)
      bf[ni] = *(const bh8*)(&Bs[cur][boff[ni]]);
    // two mi-halves to bound register pressure (af reused)
#pragma unroll
    for (int mi = 0; mi < 4; ++mi)
      af[mi] = *(const bh8*)(&As[cur][aoff[mi]]);
#pragma unroll
    for (int mi = 0; mi < 4; ++mi)
#pragma unroll
      for (int ni = 0; ni < 4; ++ni)
        acc[mi][ni] = MFMA16(af[mi], bf[ni], acc[mi][ni]);
#pragma unroll
    for (int mi = 0; mi < 4; ++mi)
      af[mi] = *(const bh8*)(&As[cur][aoff[mi + 4]]);
#pragma unroll
    for (int mi = 0; mi < 4; ++mi)
#pragma unroll
      for (int ni = 0; ni < 4; ++ni)
        acc[mi + 4][ni] = MFMA16(af[mi], bf[ni], acc[mi + 4][ni]);
    cur = (cur == 2) ? 0 : cur + 1;
  }
#undef STAGE

  // epilogue: C/D layout col=l16, row=quad*4+r
  if (kChunk) {
    // split-K partial: atomic accumulate into pre-seeded fp32 out
#pragma unroll
    for (int mi = 0; mi < 8; ++mi)
#pragma unroll
      for (int ni = 0; ni < 4; ++ni) {
        const int col = bn + wn + ni*16 + l16;
#pragma unroll
        for (int r = 0; r < 4; ++r) {
          const int gr = bm + wm + mi*16 + quad*4 + r;
          atomicAdd(outF + (size_t)gr*N + col, acc[mi][ni][r]);
        }
      }
    return;
  }
#pragma unroll
  for (int mi = 0; mi < 8; ++mi) {
#pragma unroll
    for (int ni = 0; ni < 4; ++ni) {
      const int col = bn + wn + ni*16 + l16;
      float bv; short* ob; int colw; size_t rstride;
      if (qkv) {
        const int cc = col >> 10;  // uniform per tile: 256-tiles don't straddle 1024
        colw = col & 1023;
        bv = (cc == 0 ? bias0 : cc == 1 ? bias1 : bias2)[colw];
        ob = (cc == 0 ? outB0 : cc == 1 ? outB1 : outB2);
        rstride = 1024;
      } else {
        colw = col; bv = bias0 ? bias0[col] : 0.f; ob = outB0; rstride = N;
      }
#pragma unroll
      for (int r = 0; r < 4; ++r) {
        const int gr = bm + wm + mi*16 + quad*4 + r;
        float v = acc[mi][ni][r] + bv;
        if (gelu) v = 0.5f*v*(1.f + erff(v*0.70710678f));
        if (residF) v += residF[(size_t)gr*N + col];
        if (residB) v += b2f(residB[(size_t)gr*N + col]);
        if (outF) outF[(size_t)gr*N + col] = v;
        if (ob)   ob[(size_t)gr*rstride + colw] = f2b(v);
      }
    }
  }
}

// ---------------- MFMA flash attention v2: 64-key tiles, vectorized staging -------
// grid (bh=32, 32); qt reversed so heaviest causal blocks dispatch first.
__global__ __launch_bounds__(256) void attn_kernel(const short* __restrict__ Qb,
                                                   const short* __restrict__ Kb,
                                                   const short* __restrict__ VT,
                                                   short* __restrict__ AOb) {
  __shared__ short Klds[64*72];     // [key][d]
  __shared__ short Vlds[64*72];     // [d][key]
  __shared__ short Plds[4*16*72];   // per-wave P 16x64
  const int tid = threadIdx.x;
  const int w = tid >> 6, L = tid & 63, quad = L >> 4, l16 = L & 15;
  const int bh = blockIdx.x, qt = 31 - (int)blockIdx.y;
  const int b = bh >> 4, h = bh & 15;
  const int qbase = qt*64 + w*16;

  // Q fragments, A-layout
  const size_t qrow = ((size_t)(b*SLEN + qbase + l16))*EMBED + h*HD;
  const bh8 aq0 = *(const bh8*)(Qb + qrow + quad*8);
  const bh8 aq1 = *(const bh8*)(Qb + qrow + 32 + quad*8);

  f32x4 o[4];
#pragma unroll
  for (int i = 0; i < 4; ++i) o[i] = (f32x4){0.f,0.f,0.f,0.f};
  float m_r[4] = {-1e30f,-1e30f,-1e30f,-1e30f};
  float l_r[4] = {0.f,0.f,0.f,0.f};
  const float scale = 0.125f;
  const size_t kg = ((size_t)(b*SLEN))*EMBED + h*HD;   // K base
  const size_t vg = ((size_t)(bh*HD))*SLEN;            // VT base
  const int r0 = tid >> 3, ch = tid & 7;               // staging: rows r0,r0+32; 16B chunk ch

  for (int kt = 0; kt <= qt; ++kt) {
    const int k0 = kt*64;
    __syncthreads();                                   // prev-iter readers done
    *(bh8*)(Klds + r0*72 + ch*8)      = *(const bh8*)(Kb + kg + (size_t)(k0 + r0)*EMBED + ch*8);
    *(bh8*)(Klds + (r0+32)*72 + ch*8) = *(const bh8*)(Kb + kg + (size_t)(k0 + r0 + 32)*EMBED + ch*8);
    *(bh8*)(Vlds + r0*72 + ch*8)      = *(const bh8*)(VT + vg + (size_t)r0*SLEN + k0 + ch*8);
    *(bh8*)(Vlds + (r0+32)*72 + ch*8) = *(const bh8*)(VT + vg + (size_t)(r0+32)*SLEN + k0 + ch*8);
    __syncthreads();

    // S = Q K^T : 4 n-tiles of 16 keys
    f32x4 s[4];
#pragma unroll
    for (int nt = 0; nt < 4; ++nt) {
      s[nt] = (f32x4){0.f,0.f,0.f,0.f};
      const short* kp = Klds + (nt*16 + l16)*72 + quad*8;
      s[nt] = MFMA16(aq0, *(const bh8*)kp,        s[nt]);
      s[nt] = MFMA16(aq1, *(const bh8*)(kp + 32), s[nt]);
    }

    const bool lastTile = (kt == qt);
#pragma unroll
    for (int r = 0; r < 4; ++r) {
      const int q = qbase + quad*4 + r;
      float v[4];
#pragma unroll
      for (int nt = 0; nt < 4; ++nt) {
        v[nt] = s[nt][r]*scale;
        if (lastTile && (k0 + nt*16 + l16 > q)) v[nt] = -1e30f;
      }
      float mx = fmaxf(fmaxf(v[0], v[1]), fmaxf(v[2], v[3]));
#pragma unroll
      for (int off = 8; off >= 1; off >>= 1) mx = fmaxf(mx, __shfl_xor(mx, off));
      const float mnew = fmaxf(m_r[r], mx);
      const float alpha = __expf(m_r[r] - mnew);
      float p[4], rs = 0.f;
#pragma unroll
      for (int nt = 0; nt < 4; ++nt) { p[nt] = __expf(v[nt] - mnew); rs += p[nt]; }
#pragma unroll
      for (int off = 8; off >= 1; off >>= 1) rs += __shfl_xor(rs, off);
      l_r[r] = l_r[r]*alpha + rs;
      m_r[r] = mnew;
#pragma unroll
      for (int dt = 0; dt < 4; ++dt) o[dt][r] *= alpha;
      short* prow = Plds + w*1152 + (quad*4 + r)*72;
#pragma unroll
      for (int nt = 0; nt < 4; ++nt) prow[nt*16 + l16] = f2b(p[nt]);
    }

    // PV: P is wave-private (no barrier needed; in-wave LDS ordering)
    const short* pr = Plds + w*1152 + l16*72;
    const bh8 pf0 = *(const bh8*)(pr + quad*8);
    const bh8 pf1 = *(const bh8*)(pr + 32 + quad*8);
#pragma unroll
    for (int dt = 0; dt < 4; ++dt) {
      const short* vp = Vlds + (dt*16 + l16)*72 + quad*8;
      o[dt] = MFMA16(pf0, *(const bh8*)vp,        o[dt]);
      o[dt] = MFMA16(pf1, *(const bh8*)(vp + 32), o[dt]);
    }
  }

#pragma unroll
  for (int r = 0; r < 4; ++r) {
    const float inv = 1.0f / l_r[r];
    const size_t orow = ((size_t)(b*SLEN + qbase + quad*4 + r))*EMBED + h*HD;
#pragma unroll
    for (int dt = 0; dt < 4; ++dt)
      AOb[orow + dt*16 + l16] = f2b(o[dt][r]*inv);
  }
}

// ---------------- launcher ----------------
extern "C" void kernel_launch(void* const* d_in, const int* in_sizes, int n_in,
                              void* d_out, int out_size, void* d_ws, size_t ws_size,
                              hipStream_t stream) {
  const float* x    = (const float*)d_in[0];
  const float* cosb = (const float*)d_in[1];
  const float* sinb = (const float*)d_in[2];
  const float* Wq = (const float*)d_in[3];  const float* bq  = (const float*)d_in[4];
  const float* Wk = (const float*)d_in[5];  const float* bk  = (const float*)d_in[6];
  const float* Wv = (const float*)d_in[7];  const float* bv  = (const float*)d_in[8];
  const float* Wo = (const float*)d_in[9];  const float* bo  = (const float*)d_in[10];
  const float* W1 = (const float*)d_in[11]; const float* b1  = (const float*)d_in[12];
  const float* W2 = (const float*)d_in[13]; const float* b2  = (const float*)d_in[14];
  const float* g1 = (const float*)d_in[15]; const float* be1 = (const float*)d_in[16];
  const float* g2 = (const float*)d_in[17]; const float* be2 = (const float*)d_in[18];
  float* out = (float*)d_out;

  // workspace, peak 64MB
  // Phase A (prep/QKV/rope/attn):
  //   [0,6) wqkvT | [6,8) woT | [8,16) w1T | [16,24) n1b | [24,32) Qb
  //   [32,40) Kb | [40,48) Vb | [48,56) VTb | [56,64) AOb
  // Phase B (O-proj onward):
  //   [16,32) X1f (fp32, overwrites n1b+Qb) | [0,8) n2b (after O-proj) |
  //   [32,64) Hb | [0,8) w2T (after FFN1, overwrites n2b) | [8,16) free
  char* ws = (char*)d_ws;
  const size_t MB = 1ull << 20;
  short* wqkvT = (short*)(ws + 0*MB);
  short* woT = (short*)(ws + 6*MB);
  short* w1T = (short*)(ws + 8*MB);
  short* n1b = (short*)(ws + 16*MB);
  short* Qb  = (short*)(ws + 24*MB);
  short* Kb  = (short*)(ws + 32*MB);
  short* Vb  = (short*)(ws + 40*MB);
  short* VTb = (short*)(ws + 48*MB);
  short* AOb = (short*)(ws + 56*MB);
  float* X1f = (float*)(ws + 16*MB);   // 16MB fp32 X1 (= attn-out proj + x)
  short* n2b = (short*)(ws + 0*MB);    // 8MB (wqkvT/woT dead after O-proj)
  short* Hb  = (short*)(ws + 32*MB);   // 32MB (Kb/Vb/VTb/AOb dead)
  short* w2T = (short*)(ws + 0*MB);    // 8MB (n2b dead after FFN1)

  // weight prep
  transpose_w<<<dim3(16,16), 256, 0, stream>>>(Wq, wqkvT,                1024, 1024);
  transpose_w<<<dim3(16,16), 256, 0, stream>>>(Wk, wqkvT + 1024*1024,    1024, 1024);
  transpose_w<<<dim3(16,16), 256, 0, stream>>>(Wv, wqkvT + 2*1024*1024,  1024, 1024);
  transpose_w<<<dim3(16,16), 256, 0, stream>>>(Wo, woT, 1024, 1024);
  transpose_w<<<dim3(64,16), 256, 0, stream>>>(W1, w1T, 1024, 4096);

  // LN1
  ln_kernel<<<MROWS, 256, 0, stream>>>(x, nullptr, g1, be1, n1b);

  // fused QKV projection (N=3072): 256^2 tiles, 192 blocks
  gemm_bt<<<dim3(12,16), 512, 0, stream>>>(n1b, wqkvT, bq, bk, bv,
                                           nullptr, Qb, Kb, Vb, nullptr, nullptr,
                                           3072, 1024, 0, 1, 0);

  // RoPE
  rope_kernel<<<8192, 256, 0, stream>>>(Qb, Kb, cosb, sinb);

  // V transpose for attention B-frags
  transpose_v<<<dim3(32,32), 256, 0, stream>>>(Vb, VTb);

  // flash attention
  attn_kernel<<<dim3(32,32), 256, 0, stream>>>(Qb, Kb, VTb, AOb);

  // O projection + residual(x) -> X1f (fp32), split-K x4 (256 blocks)
  init_out<<<4096, 256, 0, stream>>>(bo, x, X1f);
  gemm_bt<<<dim3(4,16,4), 512, 0, stream>>>(AOb, woT, nullptr, nullptr, nullptr,
                                            X1f, nullptr, nullptr, nullptr, nullptr, nullptr,
                                            1024, 1024, 0, 0, 256);

  // LN2 (fp32 input)
  ln_kernel<<<MROWS, 256, 0, stream>>>(X1f, nullptr, g2, be2, n2b);

  // FFN1 + GELU (256 blocks)
  gemm_bt<<<dim3(16,16), 512, 0, stream>>>(n2b, w1T, b1, nullptr, nullptr,
                                           nullptr, Hb, nullptr, nullptr, nullptr, nullptr,
                                           4096, 1024, 1, 0, 0);

  // W2 transpose (n2b region freed after FFN1)
  transpose_w<<<dim3(16,64), 256, 0, stream>>>(W2, w2T, 4096, 1024);

  // FFN2 + residual(X1f) -> out (fp32), split-K x4 (256 blocks)
  init_out<<<4096, 256, 0, stream>>>(b2, X1f, out);
  gemm_bt<<<dim3(4,16,4), 512, 0, stream>>>(Hb, w2T, nullptr, nullptr, nullptr,
                                            out, nullptr, nullptr, nullptr, nullptr, nullptr,
                                            1024, 4096, 0, 0, 1024);
}

// Round 5
// 577.022 us; speedup vs baseline: 1.0735x; 1.0735x over previous
//
#include <hip/hip_runtime.h>
#include <math.h>

// ---------------- problem constants ----------------
#define EMBED 1024
#define SLEN  2048
#define BATCH 2
#define HEADS 16
#define HD    64
#define FFN_D 4096
#define MROWS (BATCH*SLEN)   // 4096

typedef short bh8  __attribute__((ext_vector_type(8)));   // 8 bf16 in 4 VGPRs
typedef float f32x4 __attribute__((ext_vector_type(4)));

#define MFMA16(a,b,c) __builtin_amdgcn_mfma_f32_16x16x32_bf16((a),(b),(c),0,0,0)
#define GLDS16(g,l) __builtin_amdgcn_global_load_lds( \
    (__attribute__((address_space(1))) void*)(g), \
    (__attribute__((address_space(3))) void*)(l), 16, 0, 0)

__device__ inline float b2f(short s) {
  union { unsigned u; float f; } c; c.u = ((unsigned)(unsigned short)s) << 16; return c.f;
}
__device__ inline short f2b(float f) {
  union { float f; unsigned u; } c; c.f = f;
  unsigned r = (c.u + 0x7FFFu + ((c.u >> 16) & 1u)) >> 16;   // RNE
  return (short)r;
}

// ---------------- weight transpose: fp32 (K,N) -> bf16 (N,K) ----------------
__global__ __launch_bounds__(256) void transpose_w(const float* __restrict__ in,
                                                   short* __restrict__ out,
                                                   int K, int N) {
  __shared__ short sm[64][65];
  const int tid = threadIdx.x;
  const int k0 = blockIdx.y * 64, n0 = blockIdx.x * 64;
#pragma unroll
  for (int it = 0; it < 16; ++it) {
    int idx = it * 256 + tid;
    int r = idx >> 6, c = idx & 63;
    sm[r][c] = f2b(in[(size_t)(k0 + r) * N + n0 + c]);
  }
  __syncthreads();
#pragma unroll
  for (int it = 0; it < 16; ++it) {
    int idx = it * 256 + tid;
    int r = idx >> 6, c = idx & 63;
    out[(size_t)(n0 + r) * K + k0 + c] = sm[c][r];
  }
}

// ---------------- V transpose: Vb[(b*S+s)*E + h*64 + d] -> VT[(bh*64+d)*S + s] ----
__global__ __launch_bounds__(256) void transpose_v(const short* __restrict__ in,
                                                   short* __restrict__ out) {
  __shared__ short sm[64][65];
  const int tid = threadIdx.x;
  const int s0 = blockIdx.x * 64, bh = blockIdx.y;
  const int b = bh >> 4, h = bh & 15;
#pragma unroll
  for (int it = 0; it < 16; ++it) {
    int idx = it * 256 + tid;
    int r = idx >> 6, c = idx & 63;     // r: s offset, c: d
    sm[r][c] = in[((size_t)(b*SLEN + s0 + r))*EMBED + h*HD + c];
  }
  __syncthreads();
#pragma unroll
  for (int it = 0; it < 16; ++it) {
    int idx = it * 256 + tid;
    int r = idx >> 6, c = idx & 63;     // r: d, c: s offset
    out[((size_t)(bh*HD + r))*SLEN + s0 + c] = sm[c][r];
  }
}

// ---------------- layernorm: one block per row (1024 cols) ----------------
__global__ __launch_bounds__(256) void ln_kernel(const float* __restrict__ inF,
                                                 const short* __restrict__ inB,
                                                 const float* __restrict__ gw,
                                                 const float* __restrict__ bw,
                                                 short* __restrict__ out) {
  const int row = blockIdx.x, tid = threadIdx.x;
  const int w = tid >> 6;
  const size_t base = (size_t)row * EMBED;
  float x[4];
#pragma unroll
  for (int i = 0; i < 4; ++i) {
    int c = tid + i * 256;
    x[i] = inF ? inF[base + c] : b2f(inB[base + c]);
  }
  float s = x[0] + x[1] + x[2] + x[3];
  float ss = x[0]*x[0] + x[1]*x[1] + x[2]*x[2] + x[3]*x[3];
#pragma unroll
  for (int off = 32; off >= 1; off >>= 1) { s += __shfl_xor(s, off); ss += __shfl_xor(ss, off); }
  __shared__ float red[8];
  if ((tid & 63) == 0) { red[w*2] = s; red[w*2+1] = ss; }
  __syncthreads();
  s  = red[0] + red[2] + red[4] + red[6];
  ss = red[1] + red[3] + red[5] + red[7];
  const float mu = s * (1.0f/EMBED);
  const float var = ss * (1.0f/EMBED) - mu*mu;
  const float rstd = rsqrtf(var + 1e-5f);
#pragma unroll
  for (int i = 0; i < 4; ++i) {
    int c = tid + i * 256;
    out[base + c] = f2b((x[i]-mu)*rstd*gw[c] + bw[c]);
  }
}

// ---------------- RoPE in-place on Q,K ----------------
__global__ __launch_bounds__(256) void rope_kernel(short* __restrict__ Qb, short* __restrict__ Kb,
                                                   const float* __restrict__ cosb,
                                                   const float* __restrict__ sinb) {
  const int idx = blockIdx.x * 256 + threadIdx.x;      // < 2M
  const int d = idx & 31;
  const int h = (idx >> 5) & 15;
  const int s = (idx >> 9) & 2047;
  const int b = idx >> 20;
  const size_t base = ((size_t)(b*SLEN + s))*EMBED + h*HD;
  const float c0 = cosb[s*HD + d],      s0 = sinb[s*HD + d];
  const float c1 = cosb[s*HD + 32 + d], s1 = sinb[s*HD + 32 + d];
  float q0 = b2f(Qb[base + d]), q1 = b2f(Qb[base + 32 + d]);
  Qb[base + d]      = f2b(q0*c0 - q1*s0);
  Qb[base + 32 + d] = f2b(q1*c1 + q0*s1);
  float k0 = b2f(Kb[base + d]), k1 = b2f(Kb[base + 32 + d]);
  Kb[base + d]      = f2b(k0*c0 - k1*s0);
  Kb[base + 32 + d] = f2b(k1*c1 + k0*s1);
}

// ---------------- epilogue seed: out = bias[col] + resid (fp32, float4) ----------
__global__ __launch_bounds__(256) void init_out(const float* __restrict__ bias,
                                                const float* __restrict__ resid,
                                                float* __restrict__ out) {
  const int idx = blockIdx.x * 256 + threadIdx.x;      // float4 index
  f32x4 r = ((const f32x4*)resid)[idx];
  const int c = (idx << 2) & 1023;
  r[0] += bias[c]; r[1] += bias[c+1]; r[2] += bias[c+2]; r[3] += bias[c+3];
  ((f32x4*)out)[idx] = r;
}

// ---------------- MFMA GEMM: 256x256, 8 waves, BK=64, 4-phase counted-vmcnt ------
// m201-family schedule (derived, race-checked):
//   K-tile (BK=64) split into 2 K-half epochs; dbuf by tile parity (LDS 128 KB).
//   Per tile, 4 phases:
//     p0: vmcnt(4); barrier; read A-lo+B frags (khalf 0) | stage A(t+1,k0) | 16 MFMA
//     p1:                    read A-hi (khalf 0, bf reused)| stage B(t+1,k0) | 16 MFMA
//     p2: vmcnt(4); barrier; read A-lo+B frags (khalf 1) | stage A(t+1,k1) | 16 MFMA
//     p3:                    read A-hi (khalf 1)          | stage B(t+1,k1) | 16 MFMA
//   Every vmcnt(4) waits only the epoch staged >=3 phases ago; in-flight never
//   drains below 4 in steady state (T4). Race safety: tile t+1 stages go to the
//   OTHER buffer; tile t+2 stages (same buffer as t) are issued only after t+1's
//   p0 barrier, which waves reach after their tile-t reads completed (lgkmcnt
//   before MFMA). 2 barriers/tile.
// LDS layout per {buf, khalf}: [row][slot0..3] 16B slots, 64 B rows; slot
// swizzle s' = s ^ ((row>>1)&3) applied BOTH sides (pre-swizzled global source
// for linear GLDS dest + same XOR on read offsets) -> 2-way reads = free
// (this exact swizzle measured 4.19M -> 0 conflicts in r1->r2).
// Waves 2(M) x 4(N); per-wave output 128x64 = acc[8][4].
// qkv=1: N=3072, route cols to outB0/1/2 (+bias0/1/2).
// kChunk>0: split-K; atomicAdd fp32 partials into pre-seeded outF.
__global__ __launch_bounds__(512, 2) void gemm_bt(const short* __restrict__ A,
                                                  const short* __restrict__ Bt,
                                                  const float* __restrict__ bias0,
                                                  const float* __restrict__ bias1,
                                                  const float* __restrict__ bias2,
                                                  float* __restrict__ outF,
                                                  short* __restrict__ outB0,
                                                  short* __restrict__ outB1,
                                                  short* __restrict__ outB2,
                                                  const float* __restrict__ residF,
                                                  const short* __restrict__ residB,
                                                  int N, int K, int gelu, int qkv,
                                                  int kChunk) {
  __shared__ short As[2*2*8192];   // [buf][khalf][256 rows][4 slots][8 shorts]
  __shared__ short Bs[2*2*8192];
  const int tid = threadIdx.x;
  const int w = tid >> 6, L = tid & 63;
  const int quad = L >> 4, l16 = L & 15;
  const int bm = blockIdx.y * 256, bn = blockIdx.x * 256;
  const int wr = w >> 2, wc = w & 3;          // 2 x 4 wave grid
  const int wm = wr * 128, wn = wc * 64;      // per-wave 128x64 output
  const int kS = kChunk ? (int)blockIdx.z * kChunk : 0;
  const int NT = (kChunk ? kChunk : K) >> 6;  // >= 4 at all call sites

  f32x4 acc[8][4];
#pragma unroll
  for (int i = 0; i < 8; ++i)
#pragma unroll
    for (int j = 0; j < 4; ++j) acc[i][j] = (f32x4){0.f,0.f,0.f,0.f};

  // staging: per {khalf, matrix}: 1024 16B chunks, 2 per thread.
  // chunk c -> row=c>>2, slot=c&3; source slot pre-swizzled.
  const int c0 = w*64 + L, c1 = 512 + w*64 + L;
  const int r0 = c0 >> 2, s0 = (c0 & 3) ^ ((r0 >> 1) & 3);
  const int r1 = c1 >> 2, s1 = (c1 & 3) ^ ((r1 >> 1) & 3);
  const short* aS0 = A  + (size_t)(bm + r0)*K + s0*8 + kS;
  const short* aS1 = A  + (size_t)(bm + r1)*K + s1*8 + kS;
  const short* bS0 = Bt + (size_t)(bn + r0)*K + s0*8 + kS;
  const short* bS1 = Bt + (size_t)(bn + r1)*K + s1*8 + kS;

  // loop-invariant swizzled read offsets (shorts; row stride 32 within a khalf)
  int aoff[8], boff[4];
#pragma unroll
  for (int mi = 0; mi < 8; ++mi) {
    const int R = wm + mi*16 + l16;
    aoff[mi] = R*32 + ((quad ^ ((R >> 1) & 3))*8);
  }
#pragma unroll
  for (int ni = 0; ni < 4; ++ni) {
    const int R = wn + ni*16 + l16;
    boff[ni] = R*32 + ((quad ^ ((R >> 1) & 3))*8);
  }

#define STA(buf, j, kof) do { \
    GLDS16(aS0 + (kof) + (j)*32, As + (buf)*16384 + (j)*8192 + c0*8); \
    GLDS16(aS1 + (kof) + (j)*32, As + (buf)*16384 + (j)*8192 + c1*8); \
  } while (0)
#define STB(buf, j, kof) do { \
    GLDS16(bS0 + (kof) + (j)*32, Bs + (buf)*16384 + (j)*8192 + c0*8); \
    GLDS16(bS1 + (kof) + (j)*32, Bs + (buf)*16384 + (j)*8192 + c1*8); \
  } while (0)

  // prologue: tile 0 fully staged (8 loads, epoch order k0 then k1)
  STA(0, 0, 0); STB(0, 0, 0); STA(0, 1, 0); STB(0, 1, 0);

  for (int t = 0; t < NT; ++t) {
    const int cb = (t & 1), ob = cb ^ 1;
    const int kof = (t + 1) << 6;
    const bool pf = (t + 1 < NT);
    const short* Asc = As + cb*16384;
    const short* Bsc = Bs + cb*16384;
    bh8 af[4], bf[4];

    // ---- p0: khalf 0, A-lo ----
    asm volatile("s_waitcnt vmcnt(4)" ::: "memory");
    __builtin_amdgcn_s_barrier();
#pragma unroll
    for (int ni = 0; ni < 4; ++ni) bf[ni] = *(const bh8*)(Bsc + boff[ni]);
#pragma unroll
    for (int mi = 0; mi < 4; ++mi) af[mi] = *(const bh8*)(Asc + aoff[mi]);
    if (pf) STA(ob, 0, kof);
    __builtin_amdgcn_s_setprio(1);
#pragma unroll
    for (int mi = 0; mi < 4; ++mi)
#pragma unroll
      for (int ni = 0; ni < 4; ++ni)
        acc[mi][ni] = MFMA16(af[mi], bf[ni], acc[mi][ni]);
    __builtin_amdgcn_s_setprio(0);

    // ---- p1: khalf 0, A-hi (bf reused) ----
#pragma unroll
    for (int mi = 0; mi < 4; ++mi) af[mi] = *(const bh8*)(Asc + aoff[mi + 4]);
    if (pf) STB(ob, 0, kof);
    __builtin_amdgcn_s_setprio(1);
#pragma unroll
    for (int mi = 0; mi < 4; ++mi)
#pragma unroll
      for (int ni = 0; ni < 4; ++ni)
        acc[mi + 4][ni] = MFMA16(af[mi], bf[ni], acc[mi + 4][ni]);
    __builtin_amdgcn_s_setprio(0);

    // ---- p2: khalf 1, A-lo ----
    if (pf) asm volatile("s_waitcnt vmcnt(4)" ::: "memory");
    else    asm volatile("s_waitcnt vmcnt(0)" ::: "memory");
    __builtin_amdgcn_s_barrier();
#pragma unroll
    for (int ni = 0; ni < 4; ++ni) bf[ni] = *(const bh8*)(Bsc + 8192 + boff[ni]);
#pragma unroll
    for (int mi = 0; mi < 4; ++mi) af[mi] = *(const bh8*)(Asc + 8192 + aoff[mi]);
    if (pf) STA(ob, 1, kof);
    __builtin_amdgcn_s_setprio(1);
#pragma unroll
    for (int mi = 0; mi < 4; ++mi)
#pragma unroll
      for (int ni = 0; ni < 4; ++ni)
        acc[mi][ni] = MFMA16(af[mi], bf[ni], acc[mi][ni]);
    __builtin_amdgcn_s_setprio(0);

    // ---- p3: khalf 1, A-hi ----
#pragma unroll
    for (int mi = 0; mi < 4; ++mi) af[mi] = *(const bh8*)(Asc + 8192 + aoff[mi + 4]);
    if (pf) STB(ob, 1, kof);
    __builtin_amdgcn_s_setprio(1);
#pragma unroll
    for (int mi = 0; mi < 4; ++mi)
#pragma unroll
      for (int ni = 0; ni < 4; ++ni)
        acc[mi + 4][ni] = MFMA16(af[mi], bf[ni], acc[mi + 4][ni]);
    __builtin_amdgcn_s_setprio(0);
  }
#undef STA
#undef STB

  // epilogue: C/D layout col=l16, row=quad*4+r
  if (kChunk) {
#pragma unroll
    for (int mi = 0; mi < 8; ++mi)
#pragma unroll
      for (int ni = 0; ni < 4; ++ni) {
        const int col = bn + wn + ni*16 + l16;
#pragma unroll
        for (int r = 0; r < 4; ++r) {
          const int gr = bm + wm + mi*16 + quad*4 + r;
          atomicAdd(outF + (size_t)gr*N + col, acc[mi][ni][r]);
        }
      }
    return;
  }
#pragma unroll
  for (int mi = 0; mi < 8; ++mi) {
#pragma unroll
    for (int ni = 0; ni < 4; ++ni) {
      const int col = bn + wn + ni*16 + l16;
      float bv; short* ob2; int colw; size_t rstride;
      if (qkv) {
        const int cc = col >> 10;  // uniform per tile: 256-tiles don't straddle 1024
        colw = col & 1023;
        bv = (cc == 0 ? bias0 : cc == 1 ? bias1 : bias2)[colw];
        ob2 = (cc == 0 ? outB0 : cc == 1 ? outB1 : outB2);
        rstride = 1024;
      } else {
        colw = col; bv = bias0 ? bias0[col] : 0.f; ob2 = outB0; rstride = N;
      }
#pragma unroll
      for (int r = 0; r < 4; ++r) {
        const int gr = bm + wm + mi*16 + quad*4 + r;
        float v = acc[mi][ni][r] + bv;
        if (gelu) v = 0.5f*v*(1.f + erff(v*0.70710678f));
        if (residF) v += residF[(size_t)gr*N + col];
        if (residB) v += b2f(residB[(size_t)gr*N + col]);
        if (outF) outF[(size_t)gr*N + col] = v;
        if (ob2)  ob2[(size_t)gr*rstride + colw] = f2b(v);
      }
    }
  }
}

// ---------------- MFMA flash attention v2: 64-key tiles, vectorized staging -------
__global__ __launch_bounds__(256) void attn_kernel(const short* __restrict__ Qb,
                                                   const short* __restrict__ Kb,
                                                   const short* __restrict__ VT,
                                                   short* __restrict__ AOb) {
  __shared__ short Klds[64*72];     // [key][d]
  __shared__ short Vlds[64*72];     // [d][key]
  __shared__ short Plds[4*16*72];   // per-wave P 16x64
  const int tid = threadIdx.x;
  const int w = tid >> 6, L = tid & 63, quad = L >> 4, l16 = L & 15;
  const int bh = blockIdx.x, qt = 31 - (int)blockIdx.y;
  const int b = bh >> 4, h = bh & 15;
  const int qbase = qt*64 + w*16;

  const size_t qrow = ((size_t)(b*SLEN + qbase + l16))*EMBED + h*HD;
  const bh8 aq0 = *(const bh8*)(Qb + qrow + quad*8);
  const bh8 aq1 = *(const bh8*)(Qb + qrow + 32 + quad*8);

  f32x4 o[4];
#pragma unroll
  for (int i = 0; i < 4; ++i) o[i] = (f32x4){0.f,0.f,0.f,0.f};
  float m_r[4] = {-1e30f,-1e30f,-1e30f,-1e30f};
  float l_r[4] = {0.f,0.f,0.f,0.f};
  const float scale = 0.125f;
  const size_t kg = ((size_t)(b*SLEN))*EMBED + h*HD;   // K base
  const size_t vg = ((size_t)(bh*HD))*SLEN;            // VT base
  const int r0 = tid >> 3, ch = tid & 7;               // staging

  for (int kt = 0; kt <= qt; ++kt) {
    const int k0 = kt*64;
    __syncthreads();
    *(bh8*)(Klds + r0*72 + ch*8)      = *(const bh8*)(Kb + kg + (size_t)(k0 + r0)*EMBED + ch*8);
    *(bh8*)(Klds + (r0+32)*72 + ch*8) = *(const bh8*)(Kb + kg + (size_t)(k0 + r0 + 32)*EMBED + ch*8);
    *(bh8*)(Vlds + r0*72 + ch*8)      = *(const bh8*)(VT + vg + (size_t)r0*SLEN + k0 + ch*8);
    *(bh8*)(Vlds + (r0+32)*72 + ch*8) = *(const bh8*)(VT + vg + (size_t)(r0+32)*SLEN + k0 + ch*8);
    __syncthreads();

    f32x4 s[4];
#pragma unroll
    for (int nt = 0; nt < 4; ++nt) {
      s[nt] = (f32x4){0.f,0.f,0.f,0.f};
      const short* kp = Klds + (nt*16 + l16)*72 + quad*8;
      s[nt] = MFMA16(aq0, *(const bh8*)kp,        s[nt]);
      s[nt] = MFMA16(aq1, *(const bh8*)(kp + 32), s[nt]);
    }

    const bool lastTile = (kt == qt);
#pragma unroll
    for (int r = 0; r < 4; ++r) {
      const int q = qbase + quad*4 + r;
      float v[4];
#pragma unroll
      for (int nt = 0; nt < 4; ++nt) {
        v[nt] = s[nt][r]*scale;
        if (lastTile && (k0 + nt*16 + l16 > q)) v[nt] = -1e30f;
      }
      float mx = fmaxf(fmaxf(v[0], v[1]), fmaxf(v[2], v[3]));
#pragma unroll
      for (int off = 8; off >= 1; off >>= 1) mx = fmaxf(mx, __shfl_xor(mx, off));
      const float mnew = fmaxf(m_r[r], mx);
      const float alpha = __expf(m_r[r] - mnew);
      float p[4], rs = 0.f;
#pragma unroll
      for (int nt = 0; nt < 4; ++nt) { p[nt] = __expf(v[nt] - mnew); rs += p[nt]; }
#pragma unroll
      for (int off = 8; off >= 1; off >>= 1) rs += __shfl_xor(rs, off);
      l_r[r] = l_r[r]*alpha + rs;
      m_r[r] = mnew;
#pragma unroll
      for (int dt = 0; dt < 4; ++dt) o[dt][r] *= alpha;
      short* prow = Plds + w*1152 + (quad*4 + r)*72;
#pragma unroll
      for (int nt = 0; nt < 4; ++nt) prow[nt*16 + l16] = f2b(p[nt]);
    }

    const short* pr = Plds + w*1152 + l16*72;
    const bh8 pf0 = *(const bh8*)(pr + quad*8);
    const bh8 pf1 = *(const bh8*)(pr + 32 + quad*8);
#pragma unroll
    for (int dt = 0; dt < 4; ++dt) {
      const short* vp = Vlds + (dt*16 + l16)*72 + quad*8;
      o[dt] = MFMA16(pf0, *(const bh8*)vp,        o[dt]);
      o[dt] = MFMA16(pf1, *(const bh8*)(vp + 32), o[dt]);
    }
  }

#pragma unroll
  for (int r = 0; r < 4; ++r) {
    const float inv = 1.0f / l_r[r];
    const size_t orow = ((size_t)(b*SLEN + qbase + quad*4 + r))*EMBED + h*HD;
#pragma unroll
    for (int dt = 0; dt < 4; ++dt)
      AOb[orow + dt*16 + l16] = f2b(o[dt][r]*inv);
  }
}

// ---------------- launcher ----------------
extern "C" void kernel_launch(void* const* d_in, const int* in_sizes, int n_in,
                              void* d_out, int out_size, void* d_ws, size_t ws_size,
                              hipStream_t stream) {
  const float* x    = (const float*)d_in[0];
  const float* cosb = (const float*)d_in[1];
  const float* sinb = (const float*)d_in[2];
  const float* Wq = (const float*)d_in[3];  const float* bq  = (const float*)d_in[4];
  const float* Wk = (const float*)d_in[5];  const float* bk  = (const float*)d_in[6];
  const float* Wv = (const float*)d_in[7];  const float* bv  = (const float*)d_in[8];
  const float* Wo = (const float*)d_in[9];  const float* bo  = (const float*)d_in[10];
  const float* W1 = (const float*)d_in[11]; const float* b1  = (const float*)d_in[12];
  const float* W2 = (const float*)d_in[13]; const float* b2  = (const float*)d_in[14];
  const float* g1 = (const float*)d_in[15]; const float* be1 = (const float*)d_in[16];
  const float* g2 = (const float*)d_in[17]; const float* be2 = (const float*)d_in[18];
  float* out = (float*)d_out;

  // workspace, peak 64MB (same plan as r2/r3)
  char* ws = (char*)d_ws;
  const size_t MB = 1ull << 20;
  short* wqkvT = (short*)(ws + 0*MB);
  short* woT = (short*)(ws + 6*MB);
  short* w1T = (short*)(ws + 8*MB);
  short* n1b = (short*)(ws + 16*MB);
  short* Qb  = (short*)(ws + 24*MB);
  short* Kb  = (short*)(ws + 32*MB);
  short* Vb  = (short*)(ws + 40*MB);
  short* VTb = (short*)(ws + 48*MB);
  short* AOb = (short*)(ws + 56*MB);
  float* X1f = (float*)(ws + 16*MB);   // 16MB fp32 X1 (= attn-out proj + x)
  short* n2b = (short*)(ws + 0*MB);    // 8MB (wqkvT/woT dead after O-proj)
  short* Hb  = (short*)(ws + 32*MB);   // 32MB (Kb/Vb/VTb/AOb dead)
  short* w2T = (short*)(ws + 0*MB);    // 8MB (n2b dead after FFN1)

  // weight prep
  transpose_w<<<dim3(16,16), 256, 0, stream>>>(Wq, wqkvT,                1024, 1024);
  transpose_w<<<dim3(16,16), 256, 0, stream>>>(Wk, wqkvT + 1024*1024,    1024, 1024);
  transpose_w<<<dim3(16,16), 256, 0, stream>>>(Wv, wqkvT + 2*1024*1024,  1024, 1024);
  transpose_w<<<dim3(16,16), 256, 0, stream>>>(Wo, woT, 1024, 1024);
  transpose_w<<<dim3(64,16), 256, 0, stream>>>(W1, w1T, 1024, 4096);

  // LN1
  ln_kernel<<<MROWS, 256, 0, stream>>>(x, nullptr, g1, be1, n1b);

  // fused QKV projection (N=3072): 256^2 tiles, 192 blocks, NT=16
  gemm_bt<<<dim3(12,16), 512, 0, stream>>>(n1b, wqkvT, bq, bk, bv,
                                           nullptr, Qb, Kb, Vb, nullptr, nullptr,
                                           3072, 1024, 0, 1, 0);

  // RoPE
  rope_kernel<<<8192, 256, 0, stream>>>(Qb, Kb, cosb, sinb);

  // V transpose for attention B-frags
  transpose_v<<<dim3(32,32), 256, 0, stream>>>(Vb, VTb);

  // flash attention
  attn_kernel<<<dim3(32,32), 256, 0, stream>>>(Qb, Kb, VTb, AOb);

  // O projection + residual(x) -> X1f (fp32), split-K x4 (256 blocks, NT=4)
  init_out<<<4096, 256, 0, stream>>>(bo, x, X1f);
  gemm_bt<<<dim3(4,16,4), 512, 0, stream>>>(AOb, woT, nullptr, nullptr, nullptr,
                                            X1f, nullptr, nullptr, nullptr, nullptr, nullptr,
                                            1024, 1024, 0, 0, 256);

  // LN2 (fp32 input)
  ln_kernel<<<MROWS, 256, 0, stream>>>(X1f, nullptr, g2, be2, n2b);

  // FFN1 + GELU (256 blocks, NT=16)
  gemm_bt<<<dim3(16,16), 512, 0, stream>>>(n2b, w1T, b1, nullptr, nullptr,
                                           nullptr, Hb, nullptr, nullptr, nullptr, nullptr,
                                           4096, 1024, 1, 0, 0);

  // W2 transpose (n2b region freed after FFN1)
  transpose_w<<<dim3(16,64), 256, 0, stream>>>(W2, w2T, 4096, 1024);

  // FFN2 + residual(X1f) -> out (fp32), split-K x4 (256 blocks, NT=16)
  init_out<<<4096, 256, 0, stream>>>(b2, X1f, out);
  gemm_bt<<<dim3(4,16,4), 512, 0, stream>>>(Hb, w2T, nullptr, nullptr, nullptr,
                                            out, nullptr, nullptr, nullptr, nullptr, nullptr,
                                            1024, 4096, 0, 0, 1024);
}

// Round 6
// 575.069 us; speedup vs baseline: 1.0772x; 1.0034x over previous
//
#include <hip/hip_runtime.h>
#include <math.h>

// ---------------- problem constants ----------------
#define EMBED 1024
#define SLEN  2048
#define BATCH 2
#define HEADS 16
#define HD    64
#define FFN_D 4096
#define MROWS (BATCH*SLEN)   // 4096

typedef short bh8  __attribute__((ext_vector_type(8)));   // 8 bf16 in 4 VGPRs
typedef float f32x4 __attribute__((ext_vector_type(4)));
typedef __attribute__((address_space(3))) const short* lsp;  // 32-bit LDS ptr

#define MFMA16(a,b,c) __builtin_amdgcn_mfma_f32_16x16x32_bf16((a),(b),(c),0,0,0)
#define GLDS16(g,l) __builtin_amdgcn_global_load_lds( \
    (__attribute__((address_space(1))) void*)(g), \
    (__attribute__((address_space(3))) void*)(l), 16, 0, 0)
// Inline-asm LDS read: invisible to the compiler's LDS alias tracking, so it
// cannot inject s_waitcnt vmcnt(0) between global_load_lds and these reads
// (the r2/r4 invariance bug). WE enforce ordering: lgkmcnt(0)+sched_barrier
// before use (rule #18), vmcnt+barrier protocol for cross-wave visibility.
#define DSR(dst, base, IMM) \
  asm volatile("ds_read_b128 %0, %1 offset:" #IMM : "=v"(dst) : "v"(base))

__device__ inline float b2f(short s) {
  union { unsigned u; float f; } c; c.u = ((unsigned)(unsigned short)s) << 16; return c.f;
}
__device__ inline short f2b(float f) {
  union { float f; unsigned u; } c; c.f = f;
  unsigned r = (c.u + 0x7FFFu + ((c.u >> 16) & 1u)) >> 16;   // RNE
  return (short)r;
}

// ---------------- weight transpose: fp32 (K,N) -> bf16 (N,K) ----------------
__global__ __launch_bounds__(256) void transpose_w(const float* __restrict__ in,
                                                   short* __restrict__ out,
                                                   int K, int N) {
  __shared__ short sm[64][65];
  const int tid = threadIdx.x;
  const int k0 = blockIdx.y * 64, n0 = blockIdx.x * 64;
#pragma unroll
  for (int it = 0; it < 16; ++it) {
    int idx = it * 256 + tid;
    int r = idx >> 6, c = idx & 63;
    sm[r][c] = f2b(in[(size_t)(k0 + r) * N + n0 + c]);
  }
  __syncthreads();
#pragma unroll
  for (int it = 0; it < 16; ++it) {
    int idx = it * 256 + tid;
    int r = idx >> 6, c = idx & 63;
    out[(size_t)(n0 + r) * K + k0 + c] = sm[c][r];
  }
}

// ---------------- V transpose: Vb[(b*S+s)*E + h*64 + d] -> VT[(bh*64+d)*S + s] ----
__global__ __launch_bounds__(256) void transpose_v(const short* __restrict__ in,
                                                   short* __restrict__ out) {
  __shared__ short sm[64][65];
  const int tid = threadIdx.x;
  const int s0 = blockIdx.x * 64, bh = blockIdx.y;
  const int b = bh >> 4, h = bh & 15;
#pragma unroll
  for (int it = 0; it < 16; ++it) {
    int idx = it * 256 + tid;
    int r = idx >> 6, c = idx & 63;     // r: s offset, c: d
    sm[r][c] = in[((size_t)(b*SLEN + s0 + r))*EMBED + h*HD + c];
  }
  __syncthreads();
#pragma unroll
  for (int it = 0; it < 16; ++it) {
    int idx = it * 256 + tid;
    int r = idx >> 6, c = idx & 63;     // r: d, c: s offset
    out[((size_t)(bh*HD + r))*SLEN + s0 + c] = sm[c][r];
  }
}

// ---------------- layernorm: one block per row (1024 cols) ----------------
__global__ __launch_bounds__(256) void ln_kernel(const float* __restrict__ inF,
                                                 const short* __restrict__ inB,
                                                 const float* __restrict__ gw,
                                                 const float* __restrict__ bw,
                                                 short* __restrict__ out) {
  const int row = blockIdx.x, tid = threadIdx.x;
  const int w = tid >> 6;
  const size_t base = (size_t)row * EMBED;
  float x[4];
#pragma unroll
  for (int i = 0; i < 4; ++i) {
    int c = tid + i * 256;
    x[i] = inF ? inF[base + c] : b2f(inB[base + c]);
  }
  float s = x[0] + x[1] + x[2] + x[3];
  float ss = x[0]*x[0] + x[1]*x[1] + x[2]*x[2] + x[3]*x[3];
#pragma unroll
  for (int off = 32; off >= 1; off >>= 1) { s += __shfl_xor(s, off); ss += __shfl_xor(ss, off); }
  __shared__ float red[8];
  if ((tid & 63) == 0) { red[w*2] = s; red[w*2+1] = ss; }
  __syncthreads();
  s  = red[0] + red[2] + red[4] + red[6];
  ss = red[1] + red[3] + red[5] + red[7];
  const float mu = s * (1.0f/EMBED);
  const float var = ss * (1.0f/EMBED) - mu*mu;
  const float rstd = rsqrtf(var + 1e-5f);
#pragma unroll
  for (int i = 0; i < 4; ++i) {
    int c = tid + i * 256;
    out[base + c] = f2b((x[i]-mu)*rstd*gw[c] + bw[c]);
  }
}

// ---------------- RoPE in-place on Q,K ----------------
__global__ __launch_bounds__(256) void rope_kernel(short* __restrict__ Qb, short* __restrict__ Kb,
                                                   const float* __restrict__ cosb,
                                                   const float* __restrict__ sinb) {
  const int idx = blockIdx.x * 256 + threadIdx.x;      // < 2M
  const int d = idx & 31;
  const int h = (idx >> 5) & 15;
  const int s = (idx >> 9) & 2047;
  const int b = idx >> 20;
  const size_t base = ((size_t)(b*SLEN + s))*EMBED + h*HD;
  const float c0 = cosb[s*HD + d],      s0 = sinb[s*HD + d];
  const float c1 = cosb[s*HD + 32 + d], s1 = sinb[s*HD + 32 + d];
  float q0 = b2f(Qb[base + d]), q1 = b2f(Qb[base + 32 + d]);
  Qb[base + d]      = f2b(q0*c0 - q1*s0);
  Qb[base + 32 + d] = f2b(q1*c1 + q0*s1);
  float k0 = b2f(Kb[base + d]), k1 = b2f(Kb[base + 32 + d]);
  Kb[base + d]      = f2b(k0*c0 - k1*s0);
  Kb[base + 32 + d] = f2b(k1*c1 + k0*s1);
}

// ---------------- epilogue seed: out = bias[col] + resid (fp32, float4) ----------
__global__ __launch_bounds__(256) void init_out(const float* __restrict__ bias,
                                                const float* __restrict__ resid,
                                                float* __restrict__ out) {
  const int idx = blockIdx.x * 256 + threadIdx.x;      // float4 index
  f32x4 r = ((const f32x4*)resid)[idx];
  const int c = (idx << 2) & 1023;
  r[0] += bias[c]; r[1] += bias[c+1]; r[2] += bias[c+2]; r[3] += bias[c+3];
  ((f32x4*)out)[idx] = r;
}

// ---------------- MFMA GEMM: 256x256, 8 waves, BK=64, asm-ds_read 2-phase --------
// Per tile (BK=64) 2 phases (kh=0,1), dbuf by tile parity. Per phase:
//   vmcnt(12)  : certify THIS wave's 4 GLDS for (t,kh) landed (staged 4 phases ago)
//   s_barrier  : everyone certified -> (cb,kh) region globally valid
//   12x asm ds_read_b128 (8 A + 4 B frags)  [invisible to compiler aliasing]
//   lgkmcnt(0) + sched_barrier               [rule #18]
//   s_barrier  : all waves' reads done -> region free for overwrite
//   stage (t+2,kh) -> (cb,kh) (4 GLDS)       [write-after-read safe]
//   32 MFMA (setprio 1..0)
// In-flight GLDS groups: steady 12-16, never drained below 8 in the loop (T4).
// LDS: [buf2][kh2][256 rows][32 cols] shorts x (A,B) = 128 KB, 1 block/CU.
// Swizzle (verified 4.19M->0 conflicts): 16B slot s at row r holds global slot
// s ^ ((r>>1)&3); both sides (pre-swizzled GLDS source + swizzled read addr).
// Read base ptr trick: (R>>1)&3 == (l16>>1)&3 (rows differ by mult of 16), so
// per-thread base + offset:mi*1024 covers all frags.
// qkv=1: route cols to outB0/1/2. kChunk>0: split-K, atomicAdd into seeded outF.
__global__ __launch_bounds__(512, 2) void gemm_bt(const short* __restrict__ A,
                                                  const short* __restrict__ Bt,
                                                  const float* __restrict__ bias0,
                                                  const float* __restrict__ bias1,
                                                  const float* __restrict__ bias2,
                                                  float* __restrict__ outF,
                                                  short* __restrict__ outB0,
                                                  short* __restrict__ outB1,
                                                  short* __restrict__ outB2,
                                                  const float* __restrict__ residF,
                                                  const short* __restrict__ residB,
                                                  int N, int K, int gelu, int qkv,
                                                  int kChunk) {
  __shared__ short As[2*2*8192];   // [buf][kh][256][32]
  __shared__ short Bs[2*2*8192];
  const int tid = threadIdx.x;
  const int w = tid >> 6, L = tid & 63;
  const int quad = L >> 4, l16 = L & 15;

  // T1: bijective XCD swizzle of (bx,by); all call-site grids have nwg%8==0.
  int bx = blockIdx.x, by = blockIdx.y;
  {
    const int gx = gridDim.x;
    const int nwg = gx * gridDim.y;
    const int wg = by*gx + bx;
    const int swz = (wg & 7)*(nwg >> 3) + (wg >> 3);
    bx = swz % gx; by = swz / gx;
  }
  const int bm = by * 256, bn = bx * 256;
  const int wr = w >> 2, wc = w & 3;          // 2 x 4 wave grid
  const int wm = wr * 128, wn = wc * 64;      // per-wave 128x64 output
  const int kS = kChunk ? (int)blockIdx.z * kChunk : 0;
  const int NT = (kChunk ? kChunk : K) >> 6;  // >= 4 at all call sites

  f32x4 acc[8][4];
#pragma unroll
  for (int i = 0; i < 8; ++i)
#pragma unroll
    for (int j = 0; j < 4; ++j) acc[i][j] = (f32x4){0.f,0.f,0.f,0.f};

  // staging chunks: per (buf,kh,matrix) 1024 16B chunks; this thread owns c0,c1.
  // chunk c -> LDS row c>>2, slot c&3 (linear); global source slot pre-swizzled.
  const int c0i = w*64 + L, c1i = 512 + w*64 + L;
  const int r0i = c0i >> 2, s0i = (c0i & 3) ^ ((r0i >> 1) & 3);
  const int r1i = c1i >> 2, s1i = (c1i & 3) ^ ((r1i >> 1) & 3);
  const short* aG0 = A  + (size_t)(bm + r0i)*K + kS + s0i*8;
  const short* aG1 = A  + (size_t)(bm + r1i)*K + kS + s1i*8;
  const short* bG0 = Bt + (size_t)(bn + r0i)*K + kS + s0i*8;
  const short* bG1 = Bt + (size_t)(bn + r1i)*K + kS + s1i*8;

  // read base pointers (AS3, 32-bit); frag (mi,kh) = base + mi*1024 + kh*16384 B
  const int ssw = (l16 >> 1) & 3;
  lsp pA0 = (lsp)(As + (wm + l16)*32 + ((quad ^ ssw) << 3));
  lsp pB0 = (lsp)(Bs + (wn + l16)*32 + ((quad ^ ssw) << 3));
  lsp pA1 = pA0 + 16384;   // buf1 (+32768 B)
  lsp pB1 = pB0 + 16384;

#define STG(DST, G0, G1, BUF, KH, KOFF) do { \
    GLDS16(G0 + (KOFF), DST + (BUF)*16384 + (KH)*8192 + w*512); \
    GLDS16(G1 + (KOFF), DST + (BUF)*16384 + (KH)*8192 + 4096 + w*512); \
  } while (0)

  // prologue: tiles 0 (buf0), 1 (buf1); group order (0,k0)(0,k1)(1,k0)(1,k1)
  STG(As, aG0, aG1, 0, 0, 0);   STG(Bs, bG0, bG1, 0, 0, 0);
  STG(As, aG0, aG1, 0, 1, 32);  STG(Bs, bG0, bG1, 0, 1, 32);
  STG(As, aG0, aG1, 1, 0, 64);  STG(Bs, bG0, bG1, 1, 0, 64);
  STG(As, aG0, aG1, 1, 1, 96);  STG(Bs, bG0, bG1, 1, 1, 96);

  for (int t = 0; t < NT; ++t) {
    const int cb = t & 1;
    lsp Ab = cb ? pA1 : pA0;
    lsp Bb = cb ? pB1 : pB0;
    const int t2 = t + 2;
    const bool pf = t2 < NT;
    const int kofA = t2 << 6;
    bh8 af[8], bf[4];

    // ================= phase A: kh0 =================
    if (t < NT-1) asm volatile("s_waitcnt vmcnt(12)" ::: "memory");
    else          asm volatile("s_waitcnt vmcnt(4)"  ::: "memory");
    __builtin_amdgcn_s_barrier();
    DSR(af[0], Ab, 0);    DSR(af[1], Ab, 1024); DSR(af[2], Ab, 2048);
    DSR(af[3], Ab, 3072); DSR(af[4], Ab, 4096); DSR(af[5], Ab, 5120);
    DSR(af[6], Ab, 6144); DSR(af[7], Ab, 7168);
    DSR(bf[0], Bb, 0);    DSR(bf[1], Bb, 1024);
    DSR(bf[2], Bb, 2048); DSR(bf[3], Bb, 3072);
    asm volatile("s_waitcnt lgkmcnt(0)" ::: "memory");
    __builtin_amdgcn_sched_barrier(0);
    __builtin_amdgcn_s_barrier();            // all reads of (cb,kh0) done
    if (pf) { STG(As, aG0, aG1, cb, 0, kofA); STG(Bs, bG0, bG1, cb, 0, kofA); }
    __builtin_amdgcn_sched_barrier(0);
    __builtin_amdgcn_s_setprio(1);
#pragma unroll
    for (int mi = 0; mi < 8; ++mi)
#pragma unroll
      for (int ni = 0; ni < 4; ++ni)
        acc[mi][ni] = MFMA16(af[mi], bf[ni], acc[mi][ni]);
    __builtin_amdgcn_s_setprio(0);

    // ================= phase B: kh1 =================
    if (t < NT-2)       asm volatile("s_waitcnt vmcnt(12)" ::: "memory");
    else if (t == NT-2) asm volatile("s_waitcnt vmcnt(8)"  ::: "memory");
    else                asm volatile("s_waitcnt vmcnt(0)"  ::: "memory");
    __builtin_amdgcn_s_barrier();
    DSR(af[0], Ab, 16384); DSR(af[1], Ab, 17408); DSR(af[2], Ab, 18432);
    DSR(af[3], Ab, 19456); DSR(af[4], Ab, 20480); DSR(af[5], Ab, 21504);
    DSR(af[6], Ab, 22528); DSR(af[7], Ab, 23552);
    DSR(bf[0], Bb, 16384); DSR(bf[1], Bb, 17408);
    DSR(bf[2], Bb, 18432); DSR(bf[3], Bb, 19456);
    asm volatile("s_waitcnt lgkmcnt(0)" ::: "memory");
    __builtin_amdgcn_sched_barrier(0);
    __builtin_amdgcn_s_barrier();            // all reads of (cb,kh1) done
    if (pf) { STG(As, aG0, aG1, cb, 1, kofA+32); STG(Bs, bG0, bG1, cb, 1, kofA+32); }
    __builtin_amdgcn_sched_barrier(0);
    __builtin_amdgcn_s_setprio(1);
#pragma unroll
    for (int mi = 0; mi < 8; ++mi)
#pragma unroll
      for (int ni = 0; ni < 4; ++ni)
        acc[mi][ni] = MFMA16(af[mi], bf[ni], acc[mi][ni]);
    __builtin_amdgcn_s_setprio(0);
  }
#undef STG

  // epilogue: C/D layout col=l16, row=quad*4+r
  if (kChunk) {
#pragma unroll
    for (int mi = 0; mi < 8; ++mi)
#pragma unroll
      for (int ni = 0; ni < 4; ++ni) {
        const int col = bn + wn + ni*16 + l16;
#pragma unroll
        for (int r = 0; r < 4; ++r) {
          const int gr = bm + wm + mi*16 + quad*4 + r;
          atomicAdd(outF + (size_t)gr*N + col, acc[mi][ni][r]);
        }
      }
    return;
  }
#pragma unroll
  for (int mi = 0; mi < 8; ++mi) {
#pragma unroll
    for (int ni = 0; ni < 4; ++ni) {
      const int col = bn + wn + ni*16 + l16;
      float bv; short* ob2; int colw; size_t rstride;
      if (qkv) {
        const int cc = col >> 10;  // uniform per tile: 256-tiles don't straddle 1024
        colw = col & 1023;
        bv = (cc == 0 ? bias0 : cc == 1 ? bias1 : bias2)[colw];
        ob2 = (cc == 0 ? outB0 : cc == 1 ? outB1 : outB2);
        rstride = 1024;
      } else {
        colw = col; bv = bias0 ? bias0[col] : 0.f; ob2 = outB0; rstride = N;
      }
#pragma unroll
      for (int r = 0; r < 4; ++r) {
        const int gr = bm + wm + mi*16 + quad*4 + r;
        float v = acc[mi][ni][r] + bv;
        if (gelu) v = 0.5f*v*(1.f + erff(v*0.70710678f));
        if (residF) v += residF[(size_t)gr*N + col];
        if (residB) v += b2f(residB[(size_t)gr*N + col]);
        if (outF) outF[(size_t)gr*N + col] = v;
        if (ob2)  ob2[(size_t)gr*rstride + colw] = f2b(v);
      }
    }
  }
}

// ---------------- MFMA flash attention v2: 64-key tiles, vectorized staging -------
__global__ __launch_bounds__(256) void attn_kernel(const short* __restrict__ Qb,
                                                   const short* __restrict__ Kb,
                                                   const short* __restrict__ VT,
                                                   short* __restrict__ AOb) {
  __shared__ short Klds[64*72];     // [key][d]
  __shared__ short Vlds[64*72];     // [d][key]
  __shared__ short Plds[4*16*72];   // per-wave P 16x64
  const int tid = threadIdx.x;
  const int w = tid >> 6, L = tid & 63, quad = L >> 4, l16 = L & 15;
  const int bh = blockIdx.x, qt = 31 - (int)blockIdx.y;
  const int b = bh >> 4, h = bh & 15;
  const int qbase = qt*64 + w*16;

  const size_t qrow = ((size_t)(b*SLEN + qbase + l16))*EMBED + h*HD;
  const bh8 aq0 = *(const bh8*)(Qb + qrow + quad*8);
  const bh8 aq1 = *(const bh8*)(Qb + qrow + 32 + quad*8);

  f32x4 o[4];
#pragma unroll
  for (int i = 0; i < 4; ++i) o[i] = (f32x4){0.f,0.f,0.f,0.f};
  float m_r[4] = {-1e30f,-1e30f,-1e30f,-1e30f};
  float l_r[4] = {0.f,0.f,0.f,0.f};
  const float scale = 0.125f;
  const size_t kg = ((size_t)(b*SLEN))*EMBED + h*HD;   // K base
  const size_t vg = ((size_t)(bh*HD))*SLEN;            // VT base
  const int r0 = tid >> 3, ch = tid & 7;               // staging

  for (int kt = 0; kt <= qt; ++kt) {
    const int k0 = kt*64;
    __syncthreads();
    *(bh8*)(Klds + r0*72 + ch*8)      = *(const bh8*)(Kb + kg + (size_t)(k0 + r0)*EMBED + ch*8);
    *(bh8*)(Klds + (r0+32)*72 + ch*8) = *(const bh8*)(Kb + kg + (size_t)(k0 + r0 + 32)*EMBED + ch*8);
    *(bh8*)(Vlds + r0*72 + ch*8)      = *(const bh8*)(VT + vg + (size_t)r0*SLEN + k0 + ch*8);
    *(bh8*)(Vlds + (r0+32)*72 + ch*8) = *(const bh8*)(VT + vg + (size_t)(r0+32)*SLEN + k0 + ch*8);
    __syncthreads();

    f32x4 s[4];
#pragma unroll
    for (int nt = 0; nt < 4; ++nt) {
      s[nt] = (f32x4){0.f,0.f,0.f,0.f};
      const short* kp = Klds + (nt*16 + l16)*72 + quad*8;
      s[nt] = MFMA16(aq0, *(const bh8*)kp,        s[nt]);
      s[nt] = MFMA16(aq1, *(const bh8*)(kp + 32), s[nt]);
    }

    const bool lastTile = (kt == qt);
#pragma unroll
    for (int r = 0; r < 4; ++r) {
      const int q = qbase + quad*4 + r;
      float v[4];
#pragma unroll
      for (int nt = 0; nt < 4; ++nt) {
        v[nt] = s[nt][r]*scale;
        if (lastTile && (k0 + nt*16 + l16 > q)) v[nt] = -1e30f;
      }
      float mx = fmaxf(fmaxf(v[0], v[1]), fmaxf(v[2], v[3]));
#pragma unroll
      for (int off = 8; off >= 1; off >>= 1) mx = fmaxf(mx, __shfl_xor(mx, off));
      const float mnew = fmaxf(m_r[r], mx);
      const float alpha = __expf(m_r[r] - mnew);
      float p[4], rs = 0.f;
#pragma unroll
      for (int nt = 0; nt < 4; ++nt) { p[nt] = __expf(v[nt] - mnew); rs += p[nt]; }
#pragma unroll
      for (int off = 8; off >= 1; off >>= 1) rs += __shfl_xor(rs, off);
      l_r[r] = l_r[r]*alpha + rs;
      m_r[r] = mnew;
#pragma unroll
      for (int dt = 0; dt < 4; ++dt) o[dt][r] *= alpha;
      short* prow = Plds + w*1152 + (quad*4 + r)*72;
#pragma unroll
      for (int nt = 0; nt < 4; ++nt) prow[nt*16 + l16] = f2b(p[nt]);
    }

    const short* pr = Plds + w*1152 + l16*72;
    const bh8 pf0 = *(const bh8*)(pr + quad*8);
    const bh8 pf1 = *(const bh8*)(pr + 32 + quad*8);
#pragma unroll
    for (int dt = 0; dt < 4; ++dt) {
      const short* vp = Vlds + (dt*16 + l16)*72 + quad*8;
      o[dt] = MFMA16(pf0, *(const bh8*)vp,        o[dt]);
      o[dt] = MFMA16(pf1, *(const bh8*)(vp + 32), o[dt]);
    }
  }

#pragma unroll
  for (int r = 0; r < 4; ++r) {
    const float inv = 1.0f / l_r[r];
    const size_t orow = ((size_t)(b*SLEN + qbase + quad*4 + r))*EMBED + h*HD;
#pragma unroll
    for (int dt = 0; dt < 4; ++dt)
      AOb[orow + dt*16 + l16] = f2b(o[dt][r]*inv);
  }
}

// ---------------- launcher ----------------
extern "C" void kernel_launch(void* const* d_in, const int* in_sizes, int n_in,
                              void* d_out, int out_size, void* d_ws, size_t ws_size,
                              hipStream_t stream) {
  const float* x    = (const float*)d_in[0];
  const float* cosb = (const float*)d_in[1];
  const float* sinb = (const float*)d_in[2];
  const float* Wq = (const float*)d_in[3];  const float* bq  = (const float*)d_in[4];
  const float* Wk = (const float*)d_in[5];  const float* bk  = (const float*)d_in[6];
  const float* Wv = (const float*)d_in[7];  const float* bv  = (const float*)d_in[8];
  const float* Wo = (const float*)d_in[9];  const float* bo  = (const float*)d_in[10];
  const float* W1 = (const float*)d_in[11]; const float* b1  = (const float*)d_in[12];
  const float* W2 = (const float*)d_in[13]; const float* b2  = (const float*)d_in[14];
  const float* g1 = (const float*)d_in[15]; const float* be1 = (const float*)d_in[16];
  const float* g2 = (const float*)d_in[17]; const float* be2 = (const float*)d_in[18];
  float* out = (float*)d_out;

  // workspace, peak 64MB (same plan as r2-r4)
  char* ws = (char*)d_ws;
  const size_t MB = 1ull << 20;
  short* wqkvT = (short*)(ws + 0*MB);
  short* woT = (short*)(ws + 6*MB);
  short* w1T = (short*)(ws + 8*MB);
  short* n1b = (short*)(ws + 16*MB);
  short* Qb  = (short*)(ws + 24*MB);
  short* Kb  = (short*)(ws + 32*MB);
  short* Vb  = (short*)(ws + 40*MB);
  short* VTb = (short*)(ws + 48*MB);
  short* AOb = (short*)(ws + 56*MB);
  float* X1f = (float*)(ws + 16*MB);   // 16MB fp32 X1 (= attn-out proj + x)
  short* n2b = (short*)(ws + 0*MB);    // 8MB (wqkvT/woT dead after O-proj)
  short* Hb  = (short*)(ws + 32*MB);   // 32MB (Kb/Vb/VTb/AOb dead)
  short* w2T = (short*)(ws + 0*MB);    // 8MB (n2b dead after FFN1)

  // weight prep
  transpose_w<<<dim3(16,16), 256, 0, stream>>>(Wq, wqkvT,                1024, 1024);
  transpose_w<<<dim3(16,16), 256, 0, stream>>>(Wk, wqkvT + 1024*1024,    1024, 1024);
  transpose_w<<<dim3(16,16), 256, 0, stream>>>(Wv, wqkvT + 2*1024*1024,  1024, 1024);
  transpose_w<<<dim3(16,16), 256, 0, stream>>>(Wo, woT, 1024, 1024);
  transpose_w<<<dim3(64,16), 256, 0, stream>>>(W1, w1T, 1024, 4096);

  // LN1
  ln_kernel<<<MROWS, 256, 0, stream>>>(x, nullptr, g1, be1, n1b);

  // fused QKV projection (N=3072): 192 blocks, NT=16
  gemm_bt<<<dim3(12,16), 512, 0, stream>>>(n1b, wqkvT, bq, bk, bv,
                                           nullptr, Qb, Kb, Vb, nullptr, nullptr,
                                           3072, 1024, 0, 1, 0);

  // RoPE
  rope_kernel<<<8192, 256, 0, stream>>>(Qb, Kb, cosb, sinb);

  // V transpose for attention B-frags
  transpose_v<<<dim3(32,32), 256, 0, stream>>>(Vb, VTb);

  // flash attention
  attn_kernel<<<dim3(32,32), 256, 0, stream>>>(Qb, Kb, VTb, AOb);

  // O projection + residual(x) -> X1f (fp32), split-K x4 (256 blocks, NT=4)
  init_out<<<4096, 256, 0, stream>>>(bo, x, X1f);
  gemm_bt<<<dim3(4,16,4), 512, 0, stream>>>(AOb, woT, nullptr, nullptr, nullptr,
                                            X1f, nullptr, nullptr, nullptr, nullptr, nullptr,
                                            1024, 1024, 0, 0, 256);

  // LN2 (fp32 input)
  ln_kernel<<<MROWS, 256, 0, stream>>>(X1f, nullptr, g2, be2, n2b);

  // FFN1 + GELU (256 blocks, NT=16)
  gemm_bt<<<dim3(16,16), 512, 0, stream>>>(n2b, w1T, b1, nullptr, nullptr,
                                           nullptr, Hb, nullptr, nullptr, nullptr, nullptr,
                                           4096, 1024, 1, 0, 0);

  // W2 transpose (n2b region freed after FFN1)
  transpose_w<<<dim3(16,64), 256, 0, stream>>>(W2, w2T, 4096, 1024);

  // FFN2 + residual(X1f) -> out (fp32), split-K x4 (256 blocks, NT=16)
  init_out<<<4096, 256, 0, stream>>>(b2, X1f, out);
  gemm_bt<<<dim3(4,16,4), 512, 0, stream>>>(Hb, w2T, nullptr, nullptr, nullptr,
                                            out, nullptr, nullptr, nullptr, nullptr, nullptr,
                                            1024, 4096, 0, 0, 1024);
}

// Round 7
// 455.395 us; speedup vs baseline: 1.3602x; 1.2628x over previous
//
#include <hip/hip_runtime.h>
#include <math.h>

// ---------------- problem constants ----------------
#define EMBED 1024
#define SLEN  2048
#define BATCH 2
#define HEADS 16
#define HD    64
#define FFN_D 4096
#define MROWS (BATCH*SLEN)   // 4096

typedef short bh8  __attribute__((ext_vector_type(8)));   // 8 bf16 in 4 VGPRs
typedef float f32x4 __attribute__((ext_vector_type(4)));
typedef __attribute__((address_space(3))) const short* lsp;  // 32-bit LDS ptr

#define MFMA16(a,b,c) __builtin_amdgcn_mfma_f32_16x16x32_bf16((a),(b),(c),0,0,0)
#define GLDS16(g,l) __builtin_amdgcn_global_load_lds( \
    (__attribute__((address_space(1))) void*)(g), \
    (__attribute__((address_space(3))) void*)(l), 16, 0, 0)
// Inline-asm LDS read: invisible to the compiler's LDS alias tracking, so it
// cannot inject s_waitcnt vmcnt(0) between global_load_lds and these reads.
// WE enforce ordering: lgkmcnt(0)+sched_barrier before use (rule #18),
// vmcnt+barrier protocol for cross-wave visibility.
#define DSR(dst, base, IMM) \
  asm volatile("ds_read_b128 %0, %1 offset:" #IMM : "=v"(dst) : "v"(base))

__device__ inline float b2f(short s) {
  union { unsigned u; float f; } c; c.u = ((unsigned)(unsigned short)s) << 16; return c.f;
}
__device__ inline short f2b(float f) {
  union { float f; unsigned u; } c; c.f = f;
  unsigned r = (c.u + 0x7FFFu + ((c.u >> 16) & 1u)) >> 16;   // RNE
  return (short)r;
}

// ---------------- weight transpose: fp32 (K,N) -> bf16 (N,K) ----------------
__global__ __launch_bounds__(256) void transpose_w(const float* __restrict__ in,
                                                   short* __restrict__ out,
                                                   int K, int N) {
  __shared__ short sm[64][65];
  const int tid = threadIdx.x;
  const int k0 = blockIdx.y * 64, n0 = blockIdx.x * 64;
#pragma unroll
  for (int it = 0; it < 16; ++it) {
    int idx = it * 256 + tid;
    int r = idx >> 6, c = idx & 63;
    sm[r][c] = f2b(in[(size_t)(k0 + r) * N + n0 + c]);
  }
  __syncthreads();
#pragma unroll
  for (int it = 0; it < 16; ++it) {
    int idx = it * 256 + tid;
    int r = idx >> 6, c = idx & 63;
    out[(size_t)(n0 + r) * K + k0 + c] = sm[c][r];
  }
}

// ---------------- V transpose: Vb[(b*S+s)*E + h*64 + d] -> VT[(bh*64+d)*S + s] ----
__global__ __launch_bounds__(256) void transpose_v(const short* __restrict__ in,
                                                   short* __restrict__ out) {
  __shared__ short sm[64][65];
  const int tid = threadIdx.x;
  const int s0 = blockIdx.x * 64, bh = blockIdx.y;
  const int b = bh >> 4, h = bh & 15;
#pragma unroll
  for (int it = 0; it < 16; ++it) {
    int idx = it * 256 + tid;
    int r = idx >> 6, c = idx & 63;     // r: s offset, c: d
    sm[r][c] = in[((size_t)(b*SLEN + s0 + r))*EMBED + h*HD + c];
  }
  __syncthreads();
#pragma unroll
  for (int it = 0; it < 16; ++it) {
    int idx = it * 256 + tid;
    int r = idx >> 6, c = idx & 63;     // r: d, c: s offset
    out[((size_t)(bh*HD + r))*SLEN + s0 + c] = sm[c][r];
  }
}

// ---------------- layernorm: one block per row (1024 cols) ----------------
__global__ __launch_bounds__(256) void ln_kernel(const float* __restrict__ inF,
                                                 const short* __restrict__ inB,
                                                 const float* __restrict__ gw,
                                                 const float* __restrict__ bw,
                                                 short* __restrict__ out) {
  const int row = blockIdx.x, tid = threadIdx.x;
  const int w = tid >> 6;
  const size_t base = (size_t)row * EMBED;
  float x[4];
#pragma unroll
  for (int i = 0; i < 4; ++i) {
    int c = tid + i * 256;
    x[i] = inF ? inF[base + c] : b2f(inB[base + c]);
  }
  float s = x[0] + x[1] + x[2] + x[3];
  float ss = x[0]*x[0] + x[1]*x[1] + x[2]*x[2] + x[3]*x[3];
#pragma unroll
  for (int off = 32; off >= 1; off >>= 1) { s += __shfl_xor(s, off); ss += __shfl_xor(ss, off); }
  __shared__ float red[8];
  if ((tid & 63) == 0) { red[w*2] = s; red[w*2+1] = ss; }
  __syncthreads();
  s  = red[0] + red[2] + red[4] + red[6];
  ss = red[1] + red[3] + red[5] + red[7];
  const float mu = s * (1.0f/EMBED);
  const float var = ss * (1.0f/EMBED) - mu*mu;
  const float rstd = rsqrtf(var + 1e-5f);
#pragma unroll
  for (int i = 0; i < 4; ++i) {
    int c = tid + i * 256;
    out[base + c] = f2b((x[i]-mu)*rstd*gw[c] + bw[c]);
  }
}

// ---------------- RoPE in-place on Q,K ----------------
__global__ __launch_bounds__(256) void rope_kernel(short* __restrict__ Qb, short* __restrict__ Kb,
                                                   const float* __restrict__ cosb,
                                                   const float* __restrict__ sinb) {
  const int idx = blockIdx.x * 256 + threadIdx.x;      // < 2M
  const int d = idx & 31;
  const int h = (idx >> 5) & 15;
  const int s = (idx >> 9) & 2047;
  const int b = idx >> 20;
  const size_t base = ((size_t)(b*SLEN + s))*EMBED + h*HD;
  const float c0 = cosb[s*HD + d],      s0 = sinb[s*HD + d];
  const float c1 = cosb[s*HD + 32 + d], s1 = sinb[s*HD + 32 + d];
  float q0 = b2f(Qb[base + d]), q1 = b2f(Qb[base + 32 + d]);
  Qb[base + d]      = f2b(q0*c0 - q1*s0);
  Qb[base + 32 + d] = f2b(q1*c1 + q0*s1);
  float k0 = b2f(Kb[base + d]), k1 = b2f(Kb[base + 32 + d]);
  Kb[base + d]      = f2b(k0*c0 - k1*s0);
  Kb[base + 32 + d] = f2b(k1*c1 + k0*s1);
}

// ---------------- MFMA GEMM: 128x128, 4 waves, BK=64, asm-ds_read pipeline -------
// Geometry reverted to 128^2 (r6 post-mortem): 64 KB LDS -> 2 blocks/CU
// co-resident (m114 cross-block overlap), all grids >= 256 blocks WITHOUT
// atomic split-K (the 192 MiB/dispatch atomic write bloat is deleted).
// Pipeline kept verbatim from r5/r6 (counted vmcnt, asm ds_read, 2 barriers
// per phase, write-after-read safe):
//   per tile t (BK=64), phases kh=0,1; dbuf by tile parity:
//     vmcnt(12): certify this wave's 4 GLDS for (t,kh) landed (staged 4 phases ago)
//     s_barrier; 8x asm ds_read_b128 (4 A + 4 B); lgkmcnt(0)+sched_barrier;
//     s_barrier (reads done -> region free); stage (t+2,kh) (4 GLDS);
//     16 MFMA (setprio 1..0)
// LDS: [buf2][kh2][128 rows][32 shorts] x (A,B) = 64 KB.
// Swizzle (verified 4.19M->0 conflicts; row stride 64 B unchanged): 16B slot s
// at row r holds global slot s ^ ((r>>1)&3); both sides (pre-swizzled GLDS
// source + swizzled read addr). (R>>1)&3 == (l16>>1)&3 since wm+mi*16 is a
// multiple of 16 -> single per-thread base + offset: immediates.
// Waves 2(M) x 2(N); per-wave output 64x64 = acc[4][4] (64 AGPR).
// qkv=1: route cols to outB0/1/2 (+bias0/1/2); 128-tiles don't straddle 1024.
__global__ __launch_bounds__(256, 2) void gemm_bt(const short* __restrict__ A,
                                                  const short* __restrict__ Bt,
                                                  const float* __restrict__ bias0,
                                                  const float* __restrict__ bias1,
                                                  const float* __restrict__ bias2,
                                                  float* __restrict__ outF,
                                                  short* __restrict__ outB0,
                                                  short* __restrict__ outB1,
                                                  short* __restrict__ outB2,
                                                  const float* __restrict__ residF,
                                                  const short* __restrict__ residB,
                                                  int N, int K, int gelu, int qkv) {
  __shared__ short As[16384];   // [buf2][kh2][128][32]
  __shared__ short Bs[16384];
  const int tid = threadIdx.x;
  const int w = tid >> 6, L = tid & 63;
  const int quad = L >> 4, l16 = L & 15;

  // T1: bijective XCD swizzle of (bx,by); all call-site grids have nwg%8==0.
  int bx = blockIdx.x, by = blockIdx.y;
  {
    const int gx = gridDim.x;
    const int nwg = gx * gridDim.y;
    const int wg = by*gx + bx;
    const int swz = (wg & 7)*(nwg >> 3) + (wg >> 3);
    bx = swz % gx; by = swz / gx;
  }
  const int bm = by * 128, bn = bx * 128;
  const int wm = (w >> 1) * 64, wn = (w & 1) * 64;   // 2x2 wave grid, 64x64/wave
  const int NT = K >> 6;                              // >= 16 at all call sites

  f32x4 acc[4][4];
#pragma unroll
  for (int i = 0; i < 4; ++i)
#pragma unroll
    for (int j = 0; j < 4; ++j) acc[i][j] = (f32x4){0.f,0.f,0.f,0.f};

  // staging: per (buf,kh,matrix) 512 16B chunks; this thread owns c0=tid, c1=256+tid.
  // chunk c -> LDS row c>>2, slot c&3 (linear); global source slot pre-swizzled.
  const int c0i = tid, c1i = 256 + tid;
  const int r0i = c0i >> 2, s0i = (c0i & 3) ^ ((r0i >> 1) & 3);
  const int r1i = c1i >> 2, s1i = (c1i & 3) ^ ((r1i >> 1) & 3);
  const short* aG0 = A  + (size_t)(bm + r0i)*K + s0i*8;
  const short* aG1 = A  + (size_t)(bm + r1i)*K + s1i*8;
  const short* bG0 = Bt + (size_t)(bn + r0i)*K + s0i*8;
  const short* bG1 = Bt + (size_t)(bn + r1i)*K + s1i*8;

  // read base pointers (AS3); frag mi at +1024 B steps, kh1 at +8192 B, buf1 +16384 B
  const int ssw = (l16 >> 1) & 3;
  lsp pA0 = (lsp)(As + (wm + l16)*32 + ((quad ^ ssw) << 3));
  lsp pB0 = (lsp)(Bs + (wn + l16)*32 + ((quad ^ ssw) << 3));
  lsp pA1 = pA0 + 8192;    // buf1 (+16384 B)
  lsp pB1 = pB0 + 8192;

  // STG: stage one (matrix, buf, kh) half-tile for K-offset KOFF (2 GLDS/thread)
#define STG(DST, G0, G1, BUF, KH, KOFF) do { \
    GLDS16(G0 + (KOFF) + (KH)*32, DST + (BUF)*8192 + (KH)*4096 + w*512); \
    GLDS16(G1 + (KOFF) + (KH)*32, DST + (BUF)*8192 + (KH)*4096 + 2048 + w*512); \
  } while (0)

  // prologue: tiles 0 (buf0), 1 (buf1); group order (0,k0)(0,k1)(1,k0)(1,k1)
  STG(As, aG0, aG1, 0, 0, 0);   STG(Bs, bG0, bG1, 0, 0, 0);
  STG(As, aG0, aG1, 0, 1, 0);   STG(Bs, bG0, bG1, 0, 1, 0);
  STG(As, aG0, aG1, 1, 0, 64);  STG(Bs, bG0, bG1, 1, 0, 64);
  STG(As, aG0, aG1, 1, 1, 64);  STG(Bs, bG0, bG1, 1, 1, 64);

  for (int t = 0; t < NT; ++t) {
    const int cb = t & 1;
    lsp Ab = cb ? pA1 : pA0;
    lsp Bb = cb ? pB1 : pB0;
    const bool pf = (t + 2) < NT;
    const int kofA = (t + 2) << 6;
    bh8 af[4], bf[4];

    // ================= phase A: kh0 =================
    if (t < NT-1) asm volatile("s_waitcnt vmcnt(12)" ::: "memory");
    else          asm volatile("s_waitcnt vmcnt(4)"  ::: "memory");
    __builtin_amdgcn_s_barrier();
    DSR(af[0], Ab, 0);    DSR(af[1], Ab, 1024);
    DSR(af[2], Ab, 2048); DSR(af[3], Ab, 3072);
    DSR(bf[0], Bb, 0);    DSR(bf[1], Bb, 1024);
    DSR(bf[2], Bb, 2048); DSR(bf[3], Bb, 3072);
    asm volatile("s_waitcnt lgkmcnt(0)" ::: "memory");
    __builtin_amdgcn_sched_barrier(0);
    __builtin_amdgcn_s_barrier();            // all reads of (cb,kh0) done
    if (pf) { STG(As, aG0, aG1, cb, 0, kofA); STG(Bs, bG0, bG1, cb, 0, kofA); }
    __builtin_amdgcn_sched_barrier(0);
    __builtin_amdgcn_s_setprio(1);
#pragma unroll
    for (int mi = 0; mi < 4; ++mi)
#pragma unroll
      for (int ni = 0; ni < 4; ++ni)
        acc[mi][ni] = MFMA16(af[mi], bf[ni], acc[mi][ni]);
    __builtin_amdgcn_s_setprio(0);

    // ================= phase B: kh1 =================
    if (t < NT-2)       asm volatile("s_waitcnt vmcnt(12)" ::: "memory");
    else if (t == NT-2) asm volatile("s_waitcnt vmcnt(8)"  ::: "memory");
    else                asm volatile("s_waitcnt vmcnt(0)"  ::: "memory");
    __builtin_amdgcn_s_barrier();
    DSR(af[0], Ab, 8192);  DSR(af[1], Ab, 9216);
    DSR(af[2], Ab, 10240); DSR(af[3], Ab, 11264);
    DSR(bf[0], Bb, 8192);  DSR(bf[1], Bb, 9216);
    DSR(bf[2], Bb, 10240); DSR(bf[3], Bb, 11264);
    asm volatile("s_waitcnt lgkmcnt(0)" ::: "memory");
    __builtin_amdgcn_sched_barrier(0);
    __builtin_amdgcn_s_barrier();            // all reads of (cb,kh1) done
    if (pf) { STG(As, aG0, aG1, cb, 1, kofA); STG(Bs, bG0, bG1, cb, 1, kofA); }
    __builtin_amdgcn_sched_barrier(0);
    __builtin_amdgcn_s_setprio(1);
#pragma unroll
    for (int mi = 0; mi < 4; ++mi)
#pragma unroll
      for (int ni = 0; ni < 4; ++ni)
        acc[mi][ni] = MFMA16(af[mi], bf[ni], acc[mi][ni]);
    __builtin_amdgcn_s_setprio(0);
  }
#undef STG

  // epilogue: C/D layout col=l16, row=quad*4+r
#pragma unroll
  for (int mi = 0; mi < 4; ++mi) {
#pragma unroll
    for (int ni = 0; ni < 4; ++ni) {
      const int col = bn + wn + ni*16 + l16;
      float bv; short* ob2; int colw; size_t rstride;
      if (qkv) {
        const int cc = col >> 10;  // uniform per tile: 128-tiles don't straddle 1024
        colw = col & 1023;
        bv = (cc == 0 ? bias0 : cc == 1 ? bias1 : bias2)[colw];
        ob2 = (cc == 0 ? outB0 : cc == 1 ? outB1 : outB2);
        rstride = 1024;
      } else {
        colw = col; bv = bias0 ? bias0[col] : 0.f; ob2 = outB0; rstride = N;
      }
#pragma unroll
      for (int r = 0; r < 4; ++r) {
        const int gr = bm + wm + mi*16 + quad*4 + r;
        float v = acc[mi][ni][r] + bv;
        if (gelu) v = 0.5f*v*(1.f + erff(v*0.70710678f));
        if (residF) v += residF[(size_t)gr*N + col];
        if (residB) v += b2f(residB[(size_t)gr*N + col]);
        if (outF) outF[(size_t)gr*N + col] = v;
        if (ob2)  ob2[(size_t)gr*rstride + colw] = f2b(v);
      }
    }
  }
}

// ---------------- MFMA flash attention v2: 64-key tiles, vectorized staging -------
__global__ __launch_bounds__(256) void attn_kernel(const short* __restrict__ Qb,
                                                   const short* __restrict__ Kb,
                                                   const short* __restrict__ VT,
                                                   short* __restrict__ AOb) {
  __shared__ short Klds[64*72];     // [key][d]
  __shared__ short Vlds[64*72];     // [d][key]
  __shared__ short Plds[4*16*72];   // per-wave P 16x64
  const int tid = threadIdx.x;
  const int w = tid >> 6, L = tid & 63, quad = L >> 4, l16 = L & 15;
  const int bh = blockIdx.x, qt = 31 - (int)blockIdx.y;
  const int b = bh >> 4, h = bh & 15;
  const int qbase = qt*64 + w*16;

  const size_t qrow = ((size_t)(b*SLEN + qbase + l16))*EMBED + h*HD;
  const bh8 aq0 = *(const bh8*)(Qb + qrow + quad*8);
  const bh8 aq1 = *(const bh8*)(Qb + qrow + 32 + quad*8);

  f32x4 o[4];
#pragma unroll
  for (int i = 0; i < 4; ++i) o[i] = (f32x4){0.f,0.f,0.f,0.f};
  float m_r[4] = {-1e30f,-1e30f,-1e30f,-1e30f};
  float l_r[4] = {0.f,0.f,0.f,0.f};
  const float scale = 0.125f;
  const size_t kg = ((size_t)(b*SLEN))*EMBED + h*HD;   // K base
  const size_t vg = ((size_t)(bh*HD))*SLEN;            // VT base
  const int r0 = tid >> 3, ch = tid & 7;               // staging

  for (int kt = 0; kt <= qt; ++kt) {
    const int k0 = kt*64;
    __syncthreads();
    *(bh8*)(Klds + r0*72 + ch*8)      = *(const bh8*)(Kb + kg + (size_t)(k0 + r0)*EMBED + ch*8);
    *(bh8*)(Klds + (r0+32)*72 + ch*8) = *(const bh8*)(Kb + kg + (size_t)(k0 + r0 + 32)*EMBED + ch*8);
    *(bh8*)(Vlds + r0*72 + ch*8)      = *(const bh8*)(VT + vg + (size_t)r0*SLEN + k0 + ch*8);
    *(bh8*)(Vlds + (r0+32)*72 + ch*8) = *(const bh8*)(VT + vg + (size_t)(r0+32)*SLEN + k0 + ch*8);
    __syncthreads();

    f32x4 s[4];
#pragma unroll
    for (int nt = 0; nt < 4; ++nt) {
      s[nt] = (f32x4){0.f,0.f,0.f,0.f};
      const short* kp = Klds + (nt*16 + l16)*72 + quad*8;
      s[nt] = MFMA16(aq0, *(const bh8*)kp,        s[nt]);
      s[nt] = MFMA16(aq1, *(const bh8*)(kp + 32), s[nt]);
    }

    const bool lastTile = (kt == qt);
#pragma unroll
    for (int r = 0; r < 4; ++r) {
      const int q = qbase + quad*4 + r;
      float v[4];
#pragma unroll
      for (int nt = 0; nt < 4; ++nt) {
        v[nt] = s[nt][r]*scale;
        if (lastTile && (k0 + nt*16 + l16 > q)) v[nt] = -1e30f;
      }
      float mx = fmaxf(fmaxf(v[0], v[1]), fmaxf(v[2], v[3]));
#pragma unroll
      for (int off = 8; off >= 1; off >>= 1) mx = fmaxf(mx, __shfl_xor(mx, off));
      const float mnew = fmaxf(m_r[r], mx);
      const float alpha = __expf(m_r[r] - mnew);
      float p[4], rs = 0.f;
#pragma unroll
      for (int nt = 0; nt < 4; ++nt) { p[nt] = __expf(v[nt] - mnew); rs += p[nt]; }
#pragma unroll
      for (int off = 8; off >= 1; off >>= 1) rs += __shfl_xor(rs, off);
      l_r[r] = l_r[r]*alpha + rs;
      m_r[r] = mnew;
#pragma unroll
      for (int dt = 0; dt < 4; ++dt) o[dt][r] *= alpha;
      short* prow = Plds + w*1152 + (quad*4 + r)*72;
#pragma unroll
      for (int nt = 0; nt < 4; ++nt) prow[nt*16 + l16] = f2b(p[nt]);
    }

    const short* pr = Plds + w*1152 + l16*72;
    const bh8 pf0 = *(const bh8*)(pr + quad*8);
    const bh8 pf1 = *(const bh8*)(pr + 32 + quad*8);
#pragma unroll
    for (int dt = 0; dt < 4; ++dt) {
      const short* vp = Vlds + (dt*16 + l16)*72 + quad*8;
      o[dt] = MFMA16(pf0, *(const bh8*)vp,        o[dt]);
      o[dt] = MFMA16(pf1, *(const bh8*)(vp + 32), o[dt]);
    }
  }

#pragma unroll
  for (int r = 0; r < 4; ++r) {
    const float inv = 1.0f / l_r[r];
    const size_t orow = ((size_t)(b*SLEN + qbase + quad*4 + r))*EMBED + h*HD;
#pragma unroll
    for (int dt = 0; dt < 4; ++dt)
      AOb[orow + dt*16 + l16] = f2b(o[dt][r]*inv);
  }
}

// ---------------- launcher ----------------
extern "C" void kernel_launch(void* const* d_in, const int* in_sizes, int n_in,
                              void* d_out, int out_size, void* d_ws, size_t ws_size,
                              hipStream_t stream) {
  const float* x    = (const float*)d_in[0];
  const float* cosb = (const float*)d_in[1];
  const float* sinb = (const float*)d_in[2];
  const float* Wq = (const float*)d_in[3];  const float* bq  = (const float*)d_in[4];
  const float* Wk = (const float*)d_in[5];  const float* bk  = (const float*)d_in[6];
  const float* Wv = (const float*)d_in[7];  const float* bv  = (const float*)d_in[8];
  const float* Wo = (const float*)d_in[9];  const float* bo  = (const float*)d_in[10];
  const float* W1 = (const float*)d_in[11]; const float* b1  = (const float*)d_in[12];
  const float* W2 = (const float*)d_in[13]; const float* b2  = (const float*)d_in[14];
  const float* g1 = (const float*)d_in[15]; const float* be1 = (const float*)d_in[16];
  const float* g2 = (const float*)d_in[17]; const float* be2 = (const float*)d_in[18];
  float* out = (float*)d_out;

  // workspace, peak 64MB
  // Phase A: [0,6) wqkvT | [6,8) woT | [8,16) w1T | [16,24) n1b | [24,32) Qb
  //          [32,40) Kb | [40,48) Vb | [48,56) VTb | [56,64) AOb
  // Phase B: [16,32) X1f (fp32, overwrites n1b+Qb) | [0,8) n2b | [32,64) Hb |
  //          [0,8) w2T (after FFN1) | [8,16) free
  char* ws = (char*)d_ws;
  const size_t MB = 1ull << 20;
  short* wqkvT = (short*)(ws + 0*MB);
  short* woT = (short*)(ws + 6*MB);
  short* w1T = (short*)(ws + 8*MB);
  short* n1b = (short*)(ws + 16*MB);
  short* Qb  = (short*)(ws + 24*MB);
  short* Kb  = (short*)(ws + 32*MB);
  short* Vb  = (short*)(ws + 40*MB);
  short* VTb = (short*)(ws + 48*MB);
  short* AOb = (short*)(ws + 56*MB);
  float* X1f = (float*)(ws + 16*MB);   // 16MB fp32 X1 (= attn-out proj + bo + x)
  short* n2b = (short*)(ws + 0*MB);    // 8MB (wqkvT/woT dead after O-proj)
  short* Hb  = (short*)(ws + 32*MB);   // 32MB (Kb/Vb/VTb/AOb dead)
  short* w2T = (short*)(ws + 0*MB);    // 8MB (n2b dead after FFN1)

  // weight prep
  transpose_w<<<dim3(16,16), 256, 0, stream>>>(Wq, wqkvT,                1024, 1024);
  transpose_w<<<dim3(16,16), 256, 0, stream>>>(Wk, wqkvT + 1024*1024,    1024, 1024);
  transpose_w<<<dim3(16,16), 256, 0, stream>>>(Wv, wqkvT + 2*1024*1024,  1024, 1024);
  transpose_w<<<dim3(16,16), 256, 0, stream>>>(Wo, woT, 1024, 1024);
  transpose_w<<<dim3(64,16), 256, 0, stream>>>(W1, w1T, 1024, 4096);

  // LN1
  ln_kernel<<<MROWS, 256, 0, stream>>>(x, nullptr, g1, be1, n1b);

  // fused QKV projection (N=3072): 768 blocks, 3/CU queue depth
  gemm_bt<<<dim3(24,32), 256, 0, stream>>>(n1b, wqkvT, bq, bk, bv,
                                           nullptr, Qb, Kb, Vb, nullptr, nullptr,
                                           3072, 1024, 0, 1);

  // RoPE
  rope_kernel<<<8192, 256, 0, stream>>>(Qb, Kb, cosb, sinb);

  // V transpose for attention B-frags
  transpose_v<<<dim3(32,32), 256, 0, stream>>>(Vb, VTb);

  // flash attention
  attn_kernel<<<dim3(32,32), 256, 0, stream>>>(Qb, Kb, VTb, AOb);

  // O projection + bias + residual(x) -> X1f (fp32); 256 blocks, no split-K
  gemm_bt<<<dim3(8,32), 256, 0, stream>>>(AOb, woT, bo, nullptr, nullptr,
                                          X1f, nullptr, nullptr, nullptr, x, nullptr,
                                          1024, 1024, 0, 0);

  // LN2 (fp32 input)
  ln_kernel<<<MROWS, 256, 0, stream>>>(X1f, nullptr, g2, be2, n2b);

  // FFN1 + GELU: 1024 blocks, 4/CU queue depth
  gemm_bt<<<dim3(32,32), 256, 0, stream>>>(n2b, w1T, b1, nullptr, nullptr,
                                           nullptr, Hb, nullptr, nullptr, nullptr, nullptr,
                                           4096, 1024, 1, 0);

  // W2 transpose (n2b region freed after FFN1)
  transpose_w<<<dim3(16,64), 256, 0, stream>>>(W2, w2T, 4096, 1024);

  // FFN2 + bias + residual(X1f) -> out (fp32): 256 blocks, no split-K, no atomics
  gemm_bt<<<dim3(8,32), 256, 0, stream>>>(Hb, w2T, b2, nullptr, nullptr,
                                          out, nullptr, nullptr, nullptr, X1f, nullptr,
                                          1024, 4096, 0, 0);
}

// Round 8
// 425.418 us; speedup vs baseline: 1.4561x; 1.0705x over previous
//
#include <hip/hip_runtime.h>
#include <math.h>

// ---------------- problem constants ----------------
#define EMBED 1024
#define SLEN  2048
#define BATCH 2
#define HEADS 16
#define HD    64
#define FFN_D 4096
#define MROWS (BATCH*SLEN)   // 4096

typedef short bh8  __attribute__((ext_vector_type(8)));   // 8 bf16 in 4 VGPRs
typedef float f32x4 __attribute__((ext_vector_type(4)));
typedef __attribute__((address_space(3))) const short* lsp;  // 32-bit LDS ptr

#define MFMA16(a,b,c) __builtin_amdgcn_mfma_f32_16x16x32_bf16((a),(b),(c),0,0,0)
#define GLDS16(g,l) __builtin_amdgcn_global_load_lds( \
    (__attribute__((address_space(1))) void*)(g), \
    (__attribute__((address_space(3))) void*)(l), 16, 0, 0)
// Inline-asm LDS read: invisible to the compiler's LDS alias tracking, so it
// cannot inject s_waitcnt vmcnt(0) between global_load_lds and these reads.
// WE enforce ordering: lgkmcnt(0)+sched_barrier before use (rule #18),
// vmcnt+barrier protocol for cross-wave visibility.
#define DSR(dst, base, IMM) \
  asm volatile("ds_read_b128 %0, %1 offset:" #IMM : "=v"(dst) : "v"(base))

__device__ inline float b2f(short s) {
  union { unsigned u; float f; } c; c.u = ((unsigned)(unsigned short)s) << 16; return c.f;
}
__device__ inline short f2b(float f) {
  union { float f; unsigned u; } c; c.f = f;
  unsigned r = (c.u + 0x7FFFu + ((c.u >> 16) & 1u)) >> 16;   // RNE
  return (short)r;
}
__device__ inline float exp2a(float x) {   // native v_exp_f32 = 2^x
  float r; asm("v_exp_f32 %0, %1" : "=v"(r) : "v"(x)); return r;
}

// ---------------- weight transpose: fp32 (K,N) -> bf16 (N,K) ----------------
__global__ __launch_bounds__(256) void transpose_w(const float* __restrict__ in,
                                                   short* __restrict__ out,
                                                   int K, int N) {
  __shared__ short sm[64][65];
  const int tid = threadIdx.x;
  const int k0 = blockIdx.y * 64, n0 = blockIdx.x * 64;
#pragma unroll
  for (int it = 0; it < 16; ++it) {
    int idx = it * 256 + tid;
    int r = idx >> 6, c = idx & 63;
    sm[r][c] = f2b(in[(size_t)(k0 + r) * N + n0 + c]);
  }
  __syncthreads();
#pragma unroll
  for (int it = 0; it < 16; ++it) {
    int idx = it * 256 + tid;
    int r = idx >> 6, c = idx & 63;
    out[(size_t)(n0 + r) * K + k0 + c] = sm[c][r];
  }
}

// ---------------- V transpose: Vb[(b*S+s)*E + h*64 + d] -> VT[(bh*64+d)*S + s] ----
__global__ __launch_bounds__(256) void transpose_v(const short* __restrict__ in,
                                                   short* __restrict__ out) {
  __shared__ short sm[64][65];
  const int tid = threadIdx.x;
  const int s0 = blockIdx.x * 64, bh = blockIdx.y;
  const int b = bh >> 4, h = bh & 15;
#pragma unroll
  for (int it = 0; it < 16; ++it) {
    int idx = it * 256 + tid;
    int r = idx >> 6, c = idx & 63;     // r: s offset, c: d
    sm[r][c] = in[((size_t)(b*SLEN + s0 + r))*EMBED + h*HD + c];
  }
  __syncthreads();
#pragma unroll
  for (int it = 0; it < 16; ++it) {
    int idx = it * 256 + tid;
    int r = idx >> 6, c = idx & 63;     // r: d, c: s offset
    out[((size_t)(bh*HD + r))*SLEN + s0 + c] = sm[c][r];
  }
}

// ---------------- layernorm: one block per row (1024 cols) ----------------
__global__ __launch_bounds__(256) void ln_kernel(const float* __restrict__ inF,
                                                 const short* __restrict__ inB,
                                                 const float* __restrict__ gw,
                                                 const float* __restrict__ bw,
                                                 short* __restrict__ out) {
  const int row = blockIdx.x, tid = threadIdx.x;
  const int w = tid >> 6;
  const size_t base = (size_t)row * EMBED;
  float x[4];
#pragma unroll
  for (int i = 0; i < 4; ++i) {
    int c = tid + i * 256;
    x[i] = inF ? inF[base + c] : b2f(inB[base + c]);
  }
  float s = x[0] + x[1] + x[2] + x[3];
  float ss = x[0]*x[0] + x[1]*x[1] + x[2]*x[2] + x[3]*x[3];
#pragma unroll
  for (int off = 32; off >= 1; off >>= 1) { s += __shfl_xor(s, off); ss += __shfl_xor(ss, off); }
  __shared__ float red[8];
  if ((tid & 63) == 0) { red[w*2] = s; red[w*2+1] = ss; }
  __syncthreads();
  s  = red[0] + red[2] + red[4] + red[6];
  ss = red[1] + red[3] + red[5] + red[7];
  const float mu = s * (1.0f/EMBED);
  const float var = ss * (1.0f/EMBED) - mu*mu;
  const float rstd = rsqrtf(var + 1e-5f);
#pragma unroll
  for (int i = 0; i < 4; ++i) {
    int c = tid + i * 256;
    out[base + c] = f2b((x[i]-mu)*rstd*gw[c] + bw[c]);
  }
}

// ---------------- MFMA GEMM: 128x128, 4 waves, BK=64, asm-ds_read pipeline -------
// (r7 structure, verified 455us best; unchanged core.)
// New: qkv=1 epilogue applies RoPE in-register for Q,K (cc<=1): head-dim pair
// (d, d+32) = (ni, ni+2) of the SAME lane (wn in {0,64} -> one head per wave
// tile; d = ni*16+l16). Deletes the separate rope kernel + 32MB traffic.
__global__ __launch_bounds__(256, 2) void gemm_bt(const short* __restrict__ A,
                                                  const short* __restrict__ Bt,
                                                  const float* __restrict__ bias0,
                                                  const float* __restrict__ bias1,
                                                  const float* __restrict__ bias2,
                                                  float* __restrict__ outF,
                                                  short* __restrict__ outB0,
                                                  short* __restrict__ outB1,
                                                  short* __restrict__ outB2,
                                                  const float* __restrict__ residF,
                                                  const short* __restrict__ residB,
                                                  const float* __restrict__ ropeCos,
                                                  const float* __restrict__ ropeSin,
                                                  int N, int K, int gelu, int qkv) {
  __shared__ short As[16384];   // [buf2][kh2][128][32]
  __shared__ short Bs[16384];
  const int tid = threadIdx.x;
  const int w = tid >> 6, L = tid & 63;
  const int quad = L >> 4, l16 = L & 15;

  // T1: bijective XCD swizzle of (bx,by); all call-site grids have nwg%8==0.
  int bx = blockIdx.x, by = blockIdx.y;
  {
    const int gx = gridDim.x;
    const int nwg = gx * gridDim.y;
    const int wg = by*gx + bx;
    const int swz = (wg & 7)*(nwg >> 3) + (wg >> 3);
    bx = swz % gx; by = swz / gx;
  }
  const int bm = by * 128, bn = bx * 128;
  const int wm = (w >> 1) * 64, wn = (w & 1) * 64;   // 2x2 wave grid, 64x64/wave
  const int NT = K >> 6;                              // >= 16 at all call sites

  f32x4 acc[4][4];
#pragma unroll
  for (int i = 0; i < 4; ++i)
#pragma unroll
    for (int j = 0; j < 4; ++j) acc[i][j] = (f32x4){0.f,0.f,0.f,0.f};

  // staging: per (buf,kh,matrix) 512 16B chunks; this thread owns c0=tid, c1=256+tid.
  // chunk c -> LDS row c>>2, slot c&3 (linear); global source slot pre-swizzled.
  const int c0i = tid, c1i = 256 + tid;
  const int r0i = c0i >> 2, s0i = (c0i & 3) ^ ((r0i >> 1) & 3);
  const int r1i = c1i >> 2, s1i = (c1i & 3) ^ ((r1i >> 1) & 3);
  const short* aG0 = A  + (size_t)(bm + r0i)*K + s0i*8;
  const short* aG1 = A  + (size_t)(bm + r1i)*K + s1i*8;
  const short* bG0 = Bt + (size_t)(bn + r0i)*K + s0i*8;
  const short* bG1 = Bt + (size_t)(bn + r1i)*K + s1i*8;

  // read base pointers (AS3); frag mi at +1024 B steps, kh1 at +8192 B, buf1 +16384 B
  const int ssw = (l16 >> 1) & 3;
  lsp pA0 = (lsp)(As + (wm + l16)*32 + ((quad ^ ssw) << 3));
  lsp pB0 = (lsp)(Bs + (wn + l16)*32 + ((quad ^ ssw) << 3));
  lsp pA1 = pA0 + 8192;    // buf1 (+16384 B)
  lsp pB1 = pB0 + 8192;

  // STG: stage one (matrix, buf, kh) half-tile for K-offset KOFF (2 GLDS/thread)
#define STG(DST, G0, G1, BUF, KH, KOFF) do { \
    GLDS16(G0 + (KOFF) + (KH)*32, DST + (BUF)*8192 + (KH)*4096 + w*512); \
    GLDS16(G1 + (KOFF) + (KH)*32, DST + (BUF)*8192 + (KH)*4096 + 2048 + w*512); \
  } while (0)

  // prologue: tiles 0 (buf0), 1 (buf1); group order (0,k0)(0,k1)(1,k0)(1,k1)
  STG(As, aG0, aG1, 0, 0, 0);   STG(Bs, bG0, bG1, 0, 0, 0);
  STG(As, aG0, aG1, 0, 1, 0);   STG(Bs, bG0, bG1, 0, 1, 0);
  STG(As, aG0, aG1, 1, 0, 64);  STG(Bs, bG0, bG1, 1, 0, 64);
  STG(As, aG0, aG1, 1, 1, 64);  STG(Bs, bG0, bG1, 1, 1, 64);

  for (int t = 0; t < NT; ++t) {
    const int cb = t & 1;
    lsp Ab = cb ? pA1 : pA0;
    lsp Bb = cb ? pB1 : pB0;
    const bool pf = (t + 2) < NT;
    const int kofA = (t + 2) << 6;
    bh8 af[4], bf[4];

    // ================= phase A: kh0 =================
    if (t < NT-1) asm volatile("s_waitcnt vmcnt(12)" ::: "memory");
    else          asm volatile("s_waitcnt vmcnt(4)"  ::: "memory");
    __builtin_amdgcn_s_barrier();
    DSR(af[0], Ab, 0);    DSR(af[1], Ab, 1024);
    DSR(af[2], Ab, 2048); DSR(af[3], Ab, 3072);
    DSR(bf[0], Bb, 0);    DSR(bf[1], Bb, 1024);
    DSR(bf[2], Bb, 2048); DSR(bf[3], Bb, 3072);
    asm volatile("s_waitcnt lgkmcnt(0)" ::: "memory");
    __builtin_amdgcn_sched_barrier(0);
    __builtin_amdgcn_s_barrier();            // all reads of (cb,kh0) done
    if (pf) { STG(As, aG0, aG1, cb, 0, kofA); STG(Bs, bG0, bG1, cb, 0, kofA); }
    __builtin_amdgcn_sched_barrier(0);
    __builtin_amdgcn_s_setprio(1);
#pragma unroll
    for (int mi = 0; mi < 4; ++mi)
#pragma unroll
      for (int ni = 0; ni < 4; ++ni)
        acc[mi][ni] = MFMA16(af[mi], bf[ni], acc[mi][ni]);
    __builtin_amdgcn_s_setprio(0);

    // ================= phase B: kh1 =================
    if (t < NT-2)       asm volatile("s_waitcnt vmcnt(12)" ::: "memory");
    else if (t == NT-2) asm volatile("s_waitcnt vmcnt(8)"  ::: "memory");
    else                asm volatile("s_waitcnt vmcnt(0)"  ::: "memory");
    __builtin_amdgcn_s_barrier();
    DSR(af[0], Ab, 8192);  DSR(af[1], Ab, 9216);
    DSR(af[2], Ab, 10240); DSR(af[3], Ab, 11264);
    DSR(bf[0], Bb, 8192);  DSR(bf[1], Bb, 9216);
    DSR(bf[2], Bb, 10240); DSR(bf[3], Bb, 11264);
    asm volatile("s_waitcnt lgkmcnt(0)" ::: "memory");
    __builtin_amdgcn_sched_barrier(0);
    __builtin_amdgcn_s_barrier();            // all reads of (cb,kh1) done
    if (pf) { STG(As, aG0, aG1, cb, 1, kofA); STG(Bs, bG0, bG1, cb, 1, kofA); }
    __builtin_amdgcn_sched_barrier(0);
    __builtin_amdgcn_s_setprio(1);
#pragma unroll
    for (int mi = 0; mi < 4; ++mi)
#pragma unroll
      for (int ni = 0; ni < 4; ++ni)
        acc[mi][ni] = MFMA16(af[mi], bf[ni], acc[mi][ni]);
    __builtin_amdgcn_s_setprio(0);
  }
#undef STG

  // epilogue: C/D layout col=l16, row=quad*4+r
  if (qkv) {
    const int cc = (bn + wn) >> 10;      // uniform: 64-col wave tile in one matrix
    const float* bp = (cc == 0 ? bias0 : cc == 1 ? bias1 : bias2);
    short* ob2 = (cc == 0 ? outB0 : cc == 1 ? outB1 : outB2);
#pragma unroll
    for (int mi = 0; mi < 4; ++mi) {
      float vv[4][4];                    // [ni][r], static indexing only
#pragma unroll
      for (int ni = 0; ni < 4; ++ni) {
        const int colw = (bn + wn + ni*16 + l16) & 1023;
#pragma unroll
        for (int r = 0; r < 4; ++r) vv[ni][r] = acc[mi][ni][r] + bp[colw];
      }
      if (cc <= 1) {                     // RoPE on Q,K: pair (d, d+32) = (ni, ni+2)
#pragma unroll
        for (int nlo = 0; nlo < 2; ++nlo) {
          const int d = nlo*16 + l16;
#pragma unroll
          for (int r = 0; r < 4; ++r) {
            const int s = (bm + wm + mi*16 + quad*4 + r) & (SLEN - 1);
            const float c0 = ropeCos[s*HD + d],      s0 = ropeSin[s*HD + d];
            const float c1 = ropeCos[s*HD + 32 + d], s1 = ropeSin[s*HD + 32 + d];
            const float lo = vv[nlo][r], hi = vv[nlo + 2][r];
            vv[nlo][r]     = lo*c0 - hi*s0;
            vv[nlo + 2][r] = hi*c1 + lo*s1;
          }
        }
      }
#pragma unroll
      for (int ni = 0; ni < 4; ++ni) {
        const int colw = (bn + wn + ni*16 + l16) & 1023;
#pragma unroll
        for (int r = 0; r < 4; ++r) {
          const int gr = bm + wm + mi*16 + quad*4 + r;
          ob2[(size_t)gr*1024 + colw] = f2b(vv[ni][r]);
        }
      }
    }
    return;
  }
#pragma unroll
  for (int mi = 0; mi < 4; ++mi) {
#pragma unroll
    for (int ni = 0; ni < 4; ++ni) {
      const int col = bn + wn + ni*16 + l16;
      const float bv = bias0 ? bias0[col] : 0.f;
#pragma unroll
      for (int r = 0; r < 4; ++r) {
        const int gr = bm + wm + mi*16 + quad*4 + r;
        float v = acc[mi][ni][r] + bv;
        if (gelu) v = 0.5f*v*(1.f + erff(v*0.70710678f));
        if (residF) v += residF[(size_t)gr*N + col];
        if (residB) v += b2f(residB[(size_t)gr*N + col]);
        if (outF) outF[(size_t)gr*N + col] = v;
        if (outB0) outB0[(size_t)gr*N + col] = f2b(v);
      }
    }
  }
}

// ---------------- MFMA flash attention v3 ----------------------------------------
// r8 changes vs r7 (attn was top dispatch: 79us, VALUBusy 46%, exposed L2 latency):
//  1. T14 reg-prefetch + double-buffered K/V LDS, ONE barrier per tile.
//     Race safety: reads of buf[b] complete (lgkm waits precede that iter's
//     MFMAs) before the wave reaches the next barrier; overwrite of buf[b]
//     comes >= 1 barrier later.
//  2. exp2-domain softmax: scale folded with log2e; native v_exp_f32.
// grid (bh=32, 32); qt reversed so heaviest causal blocks dispatch first.
__global__ __launch_bounds__(256) void attn_kernel(const short* __restrict__ Qb,
                                                   const short* __restrict__ Kb,
                                                   const short* __restrict__ VT,
                                                   short* __restrict__ AOb) {
  __shared__ short Klds[2][64*72];  // [buf][key][d]
  __shared__ short Vlds[2][64*72];  // [buf][d][key]
  __shared__ short Plds[4*16*72];   // per-wave P 16x64
  const int tid = threadIdx.x;
  const int w = tid >> 6, L = tid & 63, quad = L >> 4, l16 = L & 15;
  const int bh = blockIdx.x, qt = 31 - (int)blockIdx.y;
  const int b = bh >> 4, h = bh & 15;
  const int qbase = qt*64 + w*16;

  const size_t qrow = ((size_t)(b*SLEN + qbase + l16))*EMBED + h*HD;
  const bh8 aq0 = *(const bh8*)(Qb + qrow + quad*8);
  const bh8 aq1 = *(const bh8*)(Qb + qrow + 32 + quad*8);

  f32x4 o[4];
#pragma unroll
  for (int i = 0; i < 4; ++i) o[i] = (f32x4){0.f,0.f,0.f,0.f};
  float m_r[4] = {-1e30f,-1e30f,-1e30f,-1e30f};
  float l_r[4] = {0.f,0.f,0.f,0.f};
  const float scale2 = 0.125f * 1.44269504089f;   // 1/sqrt(D) * log2(e)
  const short* KgP = Kb + ((size_t)(b*SLEN))*EMBED + h*HD;
  const short* VgP = VT + ((size_t)(bh*HD))*SLEN;
  const int r0 = tid >> 3, ch = tid & 7;          // staging: rows r0,r0+32; chunk ch

  // prefetch tile 0 into registers
  bh8 k0r, k1r, v0r, v1r;
  k0r = *(const bh8*)(KgP + (size_t)r0*EMBED + ch*8);
  k1r = *(const bh8*)(KgP + (size_t)(r0 + 32)*EMBED + ch*8);
  v0r = *(const bh8*)(VgP + (size_t)r0*SLEN + ch*8);
  v1r = *(const bh8*)(VgP + (size_t)(r0 + 32)*SLEN + ch*8);

  int cur = 0;
  for (int kt = 0; kt <= qt; ++kt) {
    short* Kl = Klds[cur];
    short* Vl = Vlds[cur];
    // store prefetched regs (compiler inserts vmcnt wait here; covered by
    // previous iteration's compute)
    *(bh8*)(Kl + r0*72 + ch*8)      = k0r;
    *(bh8*)(Kl + (r0+32)*72 + ch*8) = k1r;
    *(bh8*)(Vl + r0*72 + ch*8)      = v0r;
    *(bh8*)(Vl + (r0+32)*72 + ch*8) = v1r;
    __syncthreads();                              // buf[cur] valid everywhere
    if (kt < qt) {                                // issue next-tile loads early
      const int kk = (kt + 1)*64;
      k0r = *(const bh8*)(KgP + (size_t)(kk + r0)*EMBED + ch*8);
      k1r = *(const bh8*)(KgP + (size_t)(kk + r0 + 32)*EMBED + ch*8);
      v0r = *(const bh8*)(VgP + (size_t)r0*SLEN + kk + ch*8);
      v1r = *(const bh8*)(VgP + (size_t)(r0 + 32)*SLEN + kk + ch*8);
    }

    // S = Q K^T : 4 n-tiles of 16 keys
    const int k0 = kt*64;
    f32x4 s[4];
#pragma unroll
    for (int nt = 0; nt < 4; ++nt) {
      s[nt] = (f32x4){0.f,0.f,0.f,0.f};
      const short* kp = Kl + (nt*16 + l16)*72 + quad*8;
      s[nt] = MFMA16(aq0, *(const bh8*)kp,        s[nt]);
      s[nt] = MFMA16(aq1, *(const bh8*)(kp + 32), s[nt]);
    }

    const bool lastTile = (kt == qt);
#pragma unroll
    for (int r = 0; r < 4; ++r) {
      const int q = qbase + quad*4 + r;
      float v[4];
#pragma unroll
      for (int nt = 0; nt < 4; ++nt) {
        v[nt] = s[nt][r]*scale2;
        if (lastTile && (k0 + nt*16 + l16 > q)) v[nt] = -1e30f;
      }
      float mx = fmaxf(fmaxf(v[0], v[1]), fmaxf(v[2], v[3]));
#pragma unroll
      for (int off = 8; off >= 1; off >>= 1) mx = fmaxf(mx, __shfl_xor(mx, off));
      const float mnew = fmaxf(m_r[r], mx);
      const float alpha = exp2a(m_r[r] - mnew);
      float p[4], rs = 0.f;
#pragma unroll
      for (int nt = 0; nt < 4; ++nt) { p[nt] = exp2a(v[nt] - mnew); rs += p[nt]; }
#pragma unroll
      for (int off = 8; off >= 1; off >>= 1) rs += __shfl_xor(rs, off);
      l_r[r] = l_r[r]*alpha + rs;
      m_r[r] = mnew;
#pragma unroll
      for (int dt = 0; dt < 4; ++dt) o[dt][r] *= alpha;
      short* prow = Plds + w*1152 + (quad*4 + r)*72;
#pragma unroll
      for (int nt = 0; nt < 4; ++nt) prow[nt*16 + l16] = f2b(p[nt]);
    }

    // PV: P is wave-private (no barrier needed; in-wave LDS ordering)
    const short* pr = Plds + w*1152 + l16*72;
    const bh8 pf0 = *(const bh8*)(pr + quad*8);
    const bh8 pf1 = *(const bh8*)(pr + 32 + quad*8);
#pragma unroll
    for (int dt = 0; dt < 4; ++dt) {
      const short* vp = Vl + (dt*16 + l16)*72 + quad*8;
      o[dt] = MFMA16(pf0, *(const bh8*)vp,        o[dt]);
      o[dt] = MFMA16(pf1, *(const bh8*)(vp + 32), o[dt]);
    }
    cur ^= 1;
  }

#pragma unroll
  for (int r = 0; r < 4; ++r) {
    const float inv = 1.0f / l_r[r];
    const size_t orow = ((size_t)(b*SLEN + qbase + quad*4 + r))*EMBED + h*HD;
#pragma unroll
    for (int dt = 0; dt < 4; ++dt)
      AOb[orow + dt*16 + l16] = f2b(o[dt][r]*inv);
  }
}

// ---------------- launcher ----------------
extern "C" void kernel_launch(void* const* d_in, const int* in_sizes, int n_in,
                              void* d_out, int out_size, void* d_ws, size_t ws_size,
                              hipStream_t stream) {
  const float* x    = (const float*)d_in[0];
  const float* cosb = (const float*)d_in[1];
  const float* sinb = (const float*)d_in[2];
  const float* Wq = (const float*)d_in[3];  const float* bq  = (const float*)d_in[4];
  const float* Wk = (const float*)d_in[5];  const float* bk  = (const float*)d_in[6];
  const float* Wv = (const float*)d_in[7];  const float* bv  = (const float*)d_in[8];
  const float* Wo = (const float*)d_in[9];  const float* bo  = (const float*)d_in[10];
  const float* W1 = (const float*)d_in[11]; const float* b1  = (const float*)d_in[12];
  const float* W2 = (const float*)d_in[13]; const float* b2  = (const float*)d_in[14];
  const float* g1 = (const float*)d_in[15]; const float* be1 = (const float*)d_in[16];
  const float* g2 = (const float*)d_in[17]; const float* be2 = (const float*)d_in[18];
  float* out = (float*)d_out;

  // workspace, peak 64MB
  // Phase A: [0,6) wqkvT | [6,8) woT | [8,16) w1T | [16,24) n1b | [24,32) Qb
  //          [32,40) Kb | [40,48) Vb | [48,56) VTb | [56,64) AOb
  // Phase B: [16,32) X1f (fp32, overwrites n1b+Qb) | [0,8) n2b | [32,64) Hb |
  //          [0,8) w2T (after FFN1) | [8,16) free
  char* ws = (char*)d_ws;
  const size_t MB = 1ull << 20;
  short* wqkvT = (short*)(ws + 0*MB);
  short* woT = (short*)(ws + 6*MB);
  short* w1T = (short*)(ws + 8*MB);
  short* n1b = (short*)(ws + 16*MB);
  short* Qb  = (short*)(ws + 24*MB);
  short* Kb  = (short*)(ws + 32*MB);
  short* Vb  = (short*)(ws + 40*MB);
  short* VTb = (short*)(ws + 48*MB);
  short* AOb = (short*)(ws + 56*MB);
  float* X1f = (float*)(ws + 16*MB);   // 16MB fp32 X1 (= attn-out proj + bo + x)
  short* n2b = (short*)(ws + 0*MB);    // 8MB (wqkvT/woT dead after O-proj)
  short* Hb  = (short*)(ws + 32*MB);   // 32MB (Kb/Vb/VTb/AOb dead)
  short* w2T = (short*)(ws + 0*MB);    // 8MB (n2b dead after FFN1)

  // weight prep
  transpose_w<<<dim3(16,16), 256, 0, stream>>>(Wq, wqkvT,                1024, 1024);
  transpose_w<<<dim3(16,16), 256, 0, stream>>>(Wk, wqkvT + 1024*1024,    1024, 1024);
  transpose_w<<<dim3(16,16), 256, 0, stream>>>(Wv, wqkvT + 2*1024*1024,  1024, 1024);
  transpose_w<<<dim3(16,16), 256, 0, stream>>>(Wo, woT, 1024, 1024);
  transpose_w<<<dim3(64,16), 256, 0, stream>>>(W1, w1T, 1024, 4096);

  // LN1
  ln_kernel<<<MROWS, 256, 0, stream>>>(x, nullptr, g1, be1, n1b);

  // fused QKV projection + bias + RoPE (N=3072): 768 blocks
  gemm_bt<<<dim3(24,32), 256, 0, stream>>>(n1b, wqkvT, bq, bk, bv,
                                           nullptr, Qb, Kb, Vb, nullptr, nullptr,
                                           cosb, sinb, 3072, 1024, 0, 1);

  // V transpose for attention B-frags
  transpose_v<<<dim3(32,32), 256, 0, stream>>>(Vb, VTb);

  // flash attention
  attn_kernel<<<dim3(32,32), 256, 0, stream>>>(Qb, Kb, VTb, AOb);

  // O projection + bias + residual(x) -> X1f (fp32); 256 blocks
  gemm_bt<<<dim3(8,32), 256, 0, stream>>>(AOb, woT, bo, nullptr, nullptr,
                                          X1f, nullptr, nullptr, nullptr, x, nullptr,
                                          nullptr, nullptr, 1024, 1024, 0, 0);

  // LN2 (fp32 input)
  ln_kernel<<<MROWS, 256, 0, stream>>>(X1f, nullptr, g2, be2, n2b);

  // FFN1 + GELU: 1024 blocks
  gemm_bt<<<dim3(32,32), 256, 0, stream>>>(n2b, w1T, b1, nullptr, nullptr,
                                           nullptr, Hb, nullptr, nullptr, nullptr, nullptr,
                                           nullptr, nullptr, 4096, 1024, 1, 0);

  // W2 transpose (n2b region freed after FFN1)
  transpose_w<<<dim3(16,64), 256, 0, stream>>>(W2, w2T, 4096, 1024);

  // FFN2 + bias + residual(X1f) -> out (fp32): 256 blocks
  gemm_bt<<<dim3(8,32), 256, 0, stream>>>(Hb, w2T, b2, nullptr, nullptr,
                                          out, nullptr, nullptr, nullptr, X1f, nullptr,
                                          nullptr, nullptr, 1024, 4096, 0, 0);
}

// Round 9
// 404.433 us; speedup vs baseline: 1.5316x; 1.0519x over previous
//
#include <hip/hip_runtime.h>
#include <math.h>

// ---------------- problem constants ----------------
#define EMBED 1024
#define SLEN  2048
#define BATCH 2
#define HEADS 16
#define HD    64
#define FFN_D 4096
#define MROWS (BATCH*SLEN)   // 4096

typedef short bh8  __attribute__((ext_vector_type(8)));   // 8 bf16 in 4 VGPRs
typedef float f32x4 __attribute__((ext_vector_type(4)));
typedef __attribute__((address_space(3))) const short* lsp;  // 32-bit LDS ptr

#define MFMA16(a,b,c) __builtin_amdgcn_mfma_f32_16x16x32_bf16((a),(b),(c),0,0,0)
#define GLDS16(g,l) __builtin_amdgcn_global_load_lds( \
    (__attribute__((address_space(1))) void*)(g), \
    (__attribute__((address_space(3))) void*)(l), 16, 0, 0)
// Inline-asm LDS read: invisible to the compiler's LDS alias tracking, so it
// cannot inject s_waitcnt vmcnt(0) between global_load_lds and these reads.
// WE enforce ordering: lgkmcnt(0)+sched_barrier before use (rule #18),
// vmcnt+barrier protocol for cross-wave visibility.
#define DSR(dst, base, IMM) \
  asm volatile("ds_read_b128 %0, %1 offset:" #IMM : "=v"(dst) : "v"(base))

__device__ inline float b2f(short s) {
  union { unsigned u; float f; } c; c.u = ((unsigned)(unsigned short)s) << 16; return c.f;
}
__device__ inline short f2b(float f) {
  union { float f; unsigned u; } c; c.f = f;
  unsigned r = (c.u + 0x7FFFu + ((c.u >> 16) & 1u)) >> 16;   // RNE
  return (short)r;
}
__device__ inline float exp2a(float x) {   // native v_exp_f32 = 2^x
  float r; asm("v_exp_f32 %0, %1" : "=v"(r) : "v"(x)); return r;
}
__device__ inline float rcpa(float x) {    // native v_rcp_f32 (approx, ~1ulp)
  float r; asm("v_rcp_f32 %0, %1" : "=v"(r) : "v"(x)); return r;
}

// ---------------- weight transpose: fp32 (K,N) -> bf16 (N,K) ----------------
__global__ __launch_bounds__(256) void transpose_w(const float* __restrict__ in,
                                                   short* __restrict__ out,
                                                   int K, int N) {
  __shared__ short sm[64][65];
  const int tid = threadIdx.x;
  const int k0 = blockIdx.y * 64, n0 = blockIdx.x * 64;
#pragma unroll
  for (int it = 0; it < 16; ++it) {
    int idx = it * 256 + tid;
    int r = idx >> 6, c = idx & 63;
    sm[r][c] = f2b(in[(size_t)(k0 + r) * N + n0 + c]);
  }
  __syncthreads();
#pragma unroll
  for (int it = 0; it < 16; ++it) {
    int idx = it * 256 + tid;
    int r = idx >> 6, c = idx & 63;
    out[(size_t)(n0 + r) * K + k0 + c] = sm[c][r];
  }
}

// ---------------- V transpose: Vb[(b*S+s)*E + h*64 + d] -> VT[(bh*64+d)*S + s] ----
__global__ __launch_bounds__(256) void transpose_v(const short* __restrict__ in,
                                                   short* __restrict__ out) {
  __shared__ short sm[64][65];
  const int tid = threadIdx.x;
  const int s0 = blockIdx.x * 64, bh = blockIdx.y;
  const int b = bh >> 4, h = bh & 15;
#pragma unroll
  for (int it = 0; it < 16; ++it) {
    int idx = it * 256 + tid;
    int r = idx >> 6, c = idx & 63;     // r: s offset, c: d
    sm[r][c] = in[((size_t)(b*SLEN + s0 + r))*EMBED + h*HD + c];
  }
  __syncthreads();
#pragma unroll
  for (int it = 0; it < 16; ++it) {
    int idx = it * 256 + tid;
    int r = idx >> 6, c = idx & 63;     // r: d, c: s offset
    out[((size_t)(bh*HD + r))*SLEN + s0 + c] = sm[c][r];
  }
}

// ---------------- layernorm: one block per row (1024 cols) ----------------
__global__ __launch_bounds__(256) void ln_kernel(const float* __restrict__ inF,
                                                 const short* __restrict__ inB,
                                                 const float* __restrict__ gw,
                                                 const float* __restrict__ bw,
                                                 short* __restrict__ out) {
  const int row = blockIdx.x, tid = threadIdx.x;
  const int w = tid >> 6;
  const size_t base = (size_t)row * EMBED;
  float x[4];
#pragma unroll
  for (int i = 0; i < 4; ++i) {
    int c = tid + i * 256;
    x[i] = inF ? inF[base + c] : b2f(inB[base + c]);
  }
  float s = x[0] + x[1] + x[2] + x[3];
  float ss = x[0]*x[0] + x[1]*x[1] + x[2]*x[2] + x[3]*x[3];
#pragma unroll
  for (int off = 32; off >= 1; off >>= 1) { s += __shfl_xor(s, off); ss += __shfl_xor(ss, off); }
  __shared__ float red[8];
  if ((tid & 63) == 0) { red[w*2] = s; red[w*2+1] = ss; }
  __syncthreads();
  s  = red[0] + red[2] + red[4] + red[6];
  ss = red[1] + red[3] + red[5] + red[7];
  const float mu = s * (1.0f/EMBED);
  const float var = ss * (1.0f/EMBED) - mu*mu;
  const float rstd = rsqrtf(var + 1e-5f);
#pragma unroll
  for (int i = 0; i < 4; ++i) {
    int c = tid + i * 256;
    out[base + c] = f2b((x[i]-mu)*rstd*gw[c] + bw[c]);
  }
}

// ---------------- MFMA GEMM: 128x128, 4 waves, 4-slot ring, 1 barrier/phase -----
// r9 change vs r8 (FFN1 78us, MfmaUtil 18%, 2 barriers/phase): the 64 KB LDS is
// re-interpreted as a 4-slot ring of 32-K half-tiles. Per phase p (32 K):
//   vmcnt(8): certify this wave's 4 GLDS for slot p%4 landed (staged 3 phases ago)
//   s_barrier: everyone certified -> slot p%4 globally valid AND all waves'
//              phase-(p-1) reads of slot (p-1)%4 are complete
//   stage slot (p+3)%4 == (p-1)%4 (4 GLDS)   [write-after-read safe via barrier]
//   8x asm ds_read_b128 slot p%4; lgkmcnt(0)+sched_barrier; 16 MFMA (setprio)
// ONE barrier per phase (was 2). Depth-3 stages in flight -> vmcnt(8)/4/0 tail.
// LDS: [slot4][128 rows][32 shorts] x (A,B) = 64 KB, 2 blocks/CU.
// Swizzle (verified 4.19M->0 conflicts): 16B slot s at row r holds global slot
// s ^ ((r>>1)&3); both sides. (R>>1)&3 == (l16>>1)&3 -> per-thread base +
// offset: immediates (slot*8192 + mi*1024 bytes).
// qkv=1 epilogue: bias + in-register RoPE for Q,K, route to outB0/1/2.
__global__ __launch_bounds__(256, 2) void gemm_bt(const short* __restrict__ A,
                                                  const short* __restrict__ Bt,
                                                  const float* __restrict__ bias0,
                                                  const float* __restrict__ bias1,
                                                  const float* __restrict__ bias2,
                                                  float* __restrict__ outF,
                                                  short* __restrict__ outB0,
                                                  short* __restrict__ outB1,
                                                  short* __restrict__ outB2,
                                                  const float* __restrict__ residF,
                                                  const short* __restrict__ residB,
                                                  const float* __restrict__ ropeCos,
                                                  const float* __restrict__ ropeSin,
                                                  int N, int K, int gelu, int qkv) {
  __shared__ short As[16384];   // [slot4][128][32]
  __shared__ short Bs[16384];
  const int tid = threadIdx.x;
  const int w = tid >> 6, L = tid & 63;
  const int quad = L >> 4, l16 = L & 15;

  // T1: bijective XCD swizzle of (bx,by); all call-site grids have nwg%8==0.
  int bx = blockIdx.x, by = blockIdx.y;
  {
    const int gx = gridDim.x;
    const int nwg = gx * gridDim.y;
    const int wg = by*gx + bx;
    const int swz = (wg & 7)*(nwg >> 3) + (wg >> 3);
    bx = swz % gx; by = swz / gx;
  }
  const int bm = by * 128, bn = bx * 128;
  const int wm = (w >> 1) * 64, wn = (w & 1) * 64;   // 2x2 wave grid, 64x64/wave
  const int NP = K >> 5;                              // 32-K phases; %4==0 (K=1024/4096)

  f32x4 acc[4][4];
#pragma unroll
  for (int i = 0; i < 4; ++i)
#pragma unroll
    for (int j = 0; j < 4; ++j) acc[i][j] = (f32x4){0.f,0.f,0.f,0.f};

  // staging: per (slot,matrix) 512 16B chunks; this thread owns c0=tid, c1=256+tid.
  // chunk c -> LDS row c>>2, slot-word c&3 (linear); global source pre-swizzled.
  const int c0i = tid, c1i = 256 + tid;
  const int r0i = c0i >> 2, s0i = (c0i & 3) ^ ((r0i >> 1) & 3);
  const int r1i = c1i >> 2, s1i = (c1i & 3) ^ ((r1i >> 1) & 3);
  const short* aG0 = A  + (size_t)(bm + r0i)*K + s0i*8;
  const short* aG1 = A  + (size_t)(bm + r1i)*K + s1i*8;
  const short* bG0 = Bt + (size_t)(bn + r0i)*K + s0i*8;
  const short* bG1 = Bt + (size_t)(bn + r1i)*K + s1i*8;

  // read base pointers (AS3); frag mi at +1024 B, ring slot at +8192 B
  const int ssw = (l16 >> 1) & 3;
  lsp pA0 = (lsp)(As + (wm + l16)*32 + ((quad ^ ssw) << 3));
  lsp pB0 = (lsp)(Bs + (wn + l16)*32 + ((quad ^ ssw) << 3));

  // STG: stage one matrix half-tile into ring SLOT for K-offset KOFF
#define STG(DST, G0, G1, SLOT, KOFF) do { \
    GLDS16(G0 + (KOFF), DST + (SLOT)*4096 + w*512); \
    GLDS16(G1 + (KOFF), DST + (SLOT)*4096 + 2048 + w*512); \
  } while (0)

  // one ring phase; S = compile-time slot id, AO0..AO3 = byte offsets of frags
#define PH(S, AO0, AO1, AO2, AO3) do { \
    const int p = p0 + S; \
    const int rem = NP - 1 - p; \
    if (rem >= 2)      asm volatile("s_waitcnt vmcnt(8)" ::: "memory"); \
    else if (rem == 1) asm volatile("s_waitcnt vmcnt(4)" ::: "memory"); \
    else               asm volatile("s_waitcnt vmcnt(0)" ::: "memory"); \
    __builtin_amdgcn_s_barrier(); \
    if (p + 3 < NP) { \
      const int ko = (p + 3) << 5; \
      STG(As, aG0, aG1, ((S)+3)&3, ko); \
      STG(Bs, bG0, bG1, ((S)+3)&3, ko); \
    } \
    bh8 af[4], bf[4]; \
    DSR(af[0], pA0, AO0); DSR(af[1], pA0, AO1); \
    DSR(af[2], pA0, AO2); DSR(af[3], pA0, AO3); \
    DSR(bf[0], pB0, AO0); DSR(bf[1], pB0, AO1); \
    DSR(bf[2], pB0, AO2); DSR(bf[3], pB0, AO3); \
    asm volatile("s_waitcnt lgkmcnt(0)" ::: "memory"); \
    __builtin_amdgcn_sched_barrier(0); \
    __builtin_amdgcn_s_setprio(1); \
    _Pragma("unroll") \
    for (int mi = 0; mi < 4; ++mi) \
      _Pragma("unroll") \
      for (int ni = 0; ni < 4; ++ni) \
        acc[mi][ni] = MFMA16(af[mi], bf[ni], acc[mi][ni]); \
    __builtin_amdgcn_s_setprio(0); \
  } while (0)

  // prologue: stage ring slots 0,1,2 (K-offsets 0,32,64)
  STG(As, aG0, aG1, 0, 0);   STG(Bs, bG0, bG1, 0, 0);
  STG(As, aG0, aG1, 1, 32);  STG(Bs, bG0, bG1, 1, 32);
  STG(As, aG0, aG1, 2, 64);  STG(Bs, bG0, bG1, 2, 64);

  for (int p0 = 0; p0 < NP; p0 += 4) {
    PH(0, 0,     1024,  2048,  3072);
    PH(1, 8192,  9216,  10240, 11264);
    PH(2, 16384, 17408, 18432, 19456);
    PH(3, 24576, 25600, 26624, 27648);
  }
#undef PH
#undef STG

  // epilogue: C/D layout col=l16, row=quad*4+r
  if (qkv) {
    const int cc = (bn + wn) >> 10;      // uniform: 64-col wave tile in one matrix
    const float* bp = (cc == 0 ? bias0 : cc == 1 ? bias1 : bias2);
    short* ob2 = (cc == 0 ? outB0 : cc == 1 ? outB1 : outB2);
#pragma unroll
    for (int mi = 0; mi < 4; ++mi) {
      float vv[4][4];                    // [ni][r], static indexing only
#pragma unroll
      for (int ni = 0; ni < 4; ++ni) {
        const int colw = (bn + wn + ni*16 + l16) & 1023;
#pragma unroll
        for (int r = 0; r < 4; ++r) vv[ni][r] = acc[mi][ni][r] + bp[colw];
      }
      if (cc <= 1) {                     // RoPE on Q,K: pair (d, d+32) = (ni, ni+2)
#pragma unroll
        for (int nlo = 0; nlo < 2; ++nlo) {
          const int d = nlo*16 + l16;
#pragma unroll
          for (int r = 0; r < 4; ++r) {
            const int s = (bm + wm + mi*16 + quad*4 + r) & (SLEN - 1);
            const float c0 = ropeCos[s*HD + d],      s0 = ropeSin[s*HD + d];
            const float c1 = ropeCos[s*HD + 32 + d], s1 = ropeSin[s*HD + 32 + d];
            const float lo = vv[nlo][r], hi = vv[nlo + 2][r];
            vv[nlo][r]     = lo*c0 - hi*s0;
            vv[nlo + 2][r] = hi*c1 + lo*s1;
          }
        }
      }
#pragma unroll
      for (int ni = 0; ni < 4; ++ni) {
        const int colw = (bn + wn + ni*16 + l16) & 1023;
#pragma unroll
        for (int r = 0; r < 4; ++r) {
          const int gr = bm + wm + mi*16 + quad*4 + r;
          ob2[(size_t)gr*1024 + colw] = f2b(vv[ni][r]);
        }
      }
    }
    return;
  }
#pragma unroll
  for (int mi = 0; mi < 4; ++mi) {
#pragma unroll
    for (int ni = 0; ni < 4; ++ni) {
      const int col = bn + wn + ni*16 + l16;
      const float bv = bias0 ? bias0[col] : 0.f;
#pragma unroll
      for (int r = 0; r < 4; ++r) {
        const int gr = bm + wm + mi*16 + quad*4 + r;
        float v = acc[mi][ni][r] + bv;
        if (gelu) {
          // exp2-form tanh GELU: t = 2^(v*(2.3022+0.1029*v^2)); v*t/(t+1).
          // max |diff| vs erf-GELU ~3e-4 on output; ~8 ops vs ~25 for erff.
          const float x2 = v*v;
          float wv = v*(2.3022077f + 0.1029435f*x2);
          wv = fminf(wv, 80.f);          // overflow guard (t=inf -> NaN)
          const float tt = exp2a(wv);
          v = v*tt*rcpa(tt + 1.f);
        }
        if (residF) v += residF[(size_t)gr*N + col];
        if (residB) v += b2f(residB[(size_t)gr*N + col]);
        if (outF) outF[(size_t)gr*N + col] = v;
        if (outB0) outB0[(size_t)gr*N + col] = f2b(v);
      }
    }
  }
}

// ---------------- MFMA flash attention v3 ----------------------------------------
// (r8 structure, verified: reg-prefetch + dbuf K/V LDS, 1 barrier/tile,
//  exp2-domain softmax. Attn no longer in top-5 dispatches.)
__global__ __launch_bounds__(256) void attn_kernel(const short* __restrict__ Qb,
                                                   const short* __restrict__ Kb,
                                                   const short* __restrict__ VT,
                                                   short* __restrict__ AOb) {
  __shared__ short Klds[2][64*72];  // [buf][key][d]
  __shared__ short Vlds[2][64*72];  // [buf][d][key]
  __shared__ short Plds[4*16*72];   // per-wave P 16x64
  const int tid = threadIdx.x;
  const int w = tid >> 6, L = tid & 63, quad = L >> 4, l16 = L & 15;
  const int bh = blockIdx.x, qt = 31 - (int)blockIdx.y;
  const int b = bh >> 4, h = bh & 15;
  const int qbase = qt*64 + w*16;

  const size_t qrow = ((size_t)(b*SLEN + qbase + l16))*EMBED + h*HD;
  const bh8 aq0 = *(const bh8*)(Qb + qrow + quad*8);
  const bh8 aq1 = *(const bh8*)(Qb + qrow + 32 + quad*8);

  f32x4 o[4];
#pragma unroll
  for (int i = 0; i < 4; ++i) o[i] = (f32x4){0.f,0.f,0.f,0.f};
  float m_r[4] = {-1e30f,-1e30f,-1e30f,-1e30f};
  float l_r[4] = {0.f,0.f,0.f,0.f};
  const float scale2 = 0.125f * 1.44269504089f;   // 1/sqrt(D) * log2(e)
  const short* KgP = Kb + ((size_t)(b*SLEN))*EMBED + h*HD;
  const short* VgP = VT + ((size_t)(bh*HD))*SLEN;
  const int r0 = tid >> 3, ch = tid & 7;          // staging: rows r0,r0+32; chunk ch

  // prefetch tile 0 into registers
  bh8 k0r, k1r, v0r, v1r;
  k0r = *(const bh8*)(KgP + (size_t)r0*EMBED + ch*8);
  k1r = *(const bh8*)(KgP + (size_t)(r0 + 32)*EMBED + ch*8);
  v0r = *(const bh8*)(VgP + (size_t)r0*SLEN + ch*8);
  v1r = *(const bh8*)(VgP + (size_t)(r0 + 32)*SLEN + ch*8);

  int cur = 0;
  for (int kt = 0; kt <= qt; ++kt) {
    short* Kl = Klds[cur];
    short* Vl = Vlds[cur];
    *(bh8*)(Kl + r0*72 + ch*8)      = k0r;
    *(bh8*)(Kl + (r0+32)*72 + ch*8) = k1r;
    *(bh8*)(Vl + r0*72 + ch*8)      = v0r;
    *(bh8*)(Vl + (r0+32)*72 + ch*8) = v1r;
    __syncthreads();                              // buf[cur] valid everywhere
    if (kt < qt) {                                // issue next-tile loads early
      const int kk = (kt + 1)*64;
      k0r = *(const bh8*)(KgP + (size_t)(kk + r0)*EMBED + ch*8);
      k1r = *(const bh8*)(KgP + (size_t)(kk + r0 + 32)*EMBED + ch*8);
      v0r = *(const bh8*)(VgP + (size_t)r0*SLEN + kk + ch*8);
      v1r = *(const bh8*)(VgP + (size_t)(r0 + 32)*SLEN + kk + ch*8);
    }

    // S = Q K^T : 4 n-tiles of 16 keys
    const int k0 = kt*64;
    f32x4 s[4];
#pragma unroll
    for (int nt = 0; nt < 4; ++nt) {
      s[nt] = (f32x4){0.f,0.f,0.f,0.f};
      const short* kp = Kl + (nt*16 + l16)*72 + quad*8;
      s[nt] = MFMA16(aq0, *(const bh8*)kp,        s[nt]);
      s[nt] = MFMA16(aq1, *(const bh8*)(kp + 32), s[nt]);
    }

    const bool lastTile = (kt == qt);
#pragma unroll
    for (int r = 0; r < 4; ++r) {
      const int q = qbase + quad*4 + r;
      float v[4];
#pragma unroll
      for (int nt = 0; nt < 4; ++nt) {
        v[nt] = s[nt][r]*scale2;
        if (lastTile && (k0 + nt*16 + l16 > q)) v[nt] = -1e30f;
      }
      float mx = fmaxf(fmaxf(v[0], v[1]), fmaxf(v[2], v[3]));
#pragma unroll
      for (int off = 8; off >= 1; off >>= 1) mx = fmaxf(mx, __shfl_xor(mx, off));
      const float mnew = fmaxf(m_r[r], mx);
      const float alpha = exp2a(m_r[r] - mnew);
      float p[4], rs = 0.f;
#pragma unroll
      for (int nt = 0; nt < 4; ++nt) { p[nt] = exp2a(v[nt] - mnew); rs += p[nt]; }
#pragma unroll
      for (int off = 8; off >= 1; off >>= 1) rs += __shfl_xor(rs, off);
      l_r[r] = l_r[r]*alpha + rs;
      m_r[r] = mnew;
#pragma unroll
      for (int dt = 0; dt < 4; ++dt) o[dt][r] *= alpha;
      short* prow = Plds + w*1152 + (quad*4 + r)*72;
#pragma unroll
      for (int nt = 0; nt < 4; ++nt) prow[nt*16 + l16] = f2b(p[nt]);
    }

    // PV: P is wave-private (no barrier needed; in-wave LDS ordering)
    const short* pr = Plds + w*1152 + l16*72;
    const bh8 pf0 = *(const bh8*)(pr + quad*8);
    const bh8 pf1 = *(const bh8*)(pr + 32 + quad*8);
#pragma unroll
    for (int dt = 0; dt < 4; ++dt) {
      const short* vp = Vl + (dt*16 + l16)*72 + quad*8;
      o[dt] = MFMA16(pf0, *(const bh8*)vp,        o[dt]);
      o[dt] = MFMA16(pf1, *(const bh8*)(vp + 32), o[dt]);
    }
    cur ^= 1;
  }

#pragma unroll
  for (int r = 0; r < 4; ++r) {
    const float inv = 1.0f / l_r[r];
    const size_t orow = ((size_t)(b*SLEN + qbase + quad*4 + r))*EMBED + h*HD;
#pragma unroll
    for (int dt = 0; dt < 4; ++dt)
      AOb[orow + dt*16 + l16] = f2b(o[dt][r]*inv);
  }
}

// ---------------- launcher ----------------
extern "C" void kernel_launch(void* const* d_in, const int* in_sizes, int n_in,
                              void* d_out, int out_size, void* d_ws, size_t ws_size,
                              hipStream_t stream) {
  const float* x    = (const float*)d_in[0];
  const float* cosb = (const float*)d_in[1];
  const float* sinb = (const float*)d_in[2];
  const float* Wq = (const float*)d_in[3];  const float* bq  = (const float*)d_in[4];
  const float* Wk = (const float*)d_in[5];  const float* bk  = (const float*)d_in[6];
  const float* Wv = (const float*)d_in[7];  const float* bv  = (const float*)d_in[8];
  const float* Wo = (const float*)d_in[9];  const float* bo  = (const float*)d_in[10];
  const float* W1 = (const float*)d_in[11]; const float* b1  = (const float*)d_in[12];
  const float* W2 = (const float*)d_in[13]; const float* b2  = (const float*)d_in[14];
  const float* g1 = (const float*)d_in[15]; const float* be1 = (const float*)d_in[16];
  const float* g2 = (const float*)d_in[17]; const float* be2 = (const float*)d_in[18];
  float* out = (float*)d_out;

  // workspace, peak 64MB
  // Phase A: [0,6) wqkvT | [6,8) woT | [8,16) w1T | [16,24) n1b | [24,32) Qb
  //          [32,40) Kb | [40,48) Vb | [48,56) VTb | [56,64) AOb
  // Phase B: [16,32) X1f (fp32, overwrites n1b+Qb) | [0,8) n2b | [32,64) Hb |
  //          [0,8) w2T (after FFN1) | [8,16) free
  char* ws = (char*)d_ws;
  const size_t MB = 1ull << 20;
  short* wqkvT = (short*)(ws + 0*MB);
  short* woT = (short*)(ws + 6*MB);
  short* w1T = (short*)(ws + 8*MB);
  short* n1b = (short*)(ws + 16*MB);
  short* Qb  = (short*)(ws + 24*MB);
  short* Kb  = (short*)(ws + 32*MB);
  short* Vb  = (short*)(ws + 40*MB);
  short* VTb = (short*)(ws + 48*MB);
  short* AOb = (short*)(ws + 56*MB);
  float* X1f = (float*)(ws + 16*MB);   // 16MB fp32 X1 (= attn-out proj + bo + x)
  short* n2b = (short*)(ws + 0*MB);    // 8MB (wqkvT/woT dead after O-proj)
  short* Hb  = (short*)(ws + 32*MB);   // 32MB (Kb/Vb/VTb/AOb dead)
  short* w2T = (short*)(ws + 0*MB);    // 8MB (n2b dead after FFN1)

  // weight prep
  transpose_w<<<dim3(16,16), 256, 0, stream>>>(Wq, wqkvT,                1024, 1024);
  transpose_w<<<dim3(16,16), 256, 0, stream>>>(Wk, wqkvT + 1024*1024,    1024, 1024);
  transpose_w<<<dim3(16,16), 256, 0, stream>>>(Wv, wqkvT + 2*1024*1024,  1024, 1024);
  transpose_w<<<dim3(16,16), 256, 0, stream>>>(Wo, woT, 1024, 1024);
  transpose_w<<<dim3(64,16), 256, 0, stream>>>(W1, w1T, 1024, 4096);

  // LN1
  ln_kernel<<<MROWS, 256, 0, stream>>>(x, nullptr, g1, be1, n1b);

  // fused QKV projection + bias + RoPE (N=3072): 768 blocks
  gemm_bt<<<dim3(24,32), 256, 0, stream>>>(n1b, wqkvT, bq, bk, bv,
                                           nullptr, Qb, Kb, Vb, nullptr, nullptr,
                                           cosb, sinb, 3072, 1024, 0, 1);

  // V transpose for attention B-frags
  transpose_v<<<dim3(32,32), 256, 0, stream>>>(Vb, VTb);

  // flash attention
  attn_kernel<<<dim3(32,32), 256, 0, stream>>>(Qb, Kb, VTb, AOb);

  // O projection + bias + residual(x) -> X1f (fp32); 256 blocks
  gemm_bt<<<dim3(8,32), 256, 0, stream>>>(AOb, woT, bo, nullptr, nullptr,
                                          X1f, nullptr, nullptr, nullptr, x, nullptr,
                                          nullptr, nullptr, 1024, 1024, 0, 0);

  // LN2 (fp32 input)
  ln_kernel<<<MROWS, 256, 0, stream>>>(X1f, nullptr, g2, be2, n2b);

  // FFN1 + GELU: 1024 blocks
  gemm_bt<<<dim3(32,32), 256, 0, stream>>>(n2b, w1T, b1, nullptr, nullptr,
                                           nullptr, Hb, nullptr, nullptr, nullptr, nullptr,
                                           nullptr, nullptr, 4096, 1024, 1, 0);

  // W2 transpose (n2b region freed after FFN1)
  transpose_w<<<dim3(16,64), 256, 0, stream>>>(W2, w2T, 4096, 1024);

  // FFN2 + bias + residual(X1f) -> out (fp32): 256 blocks
  gemm_bt<<<dim3(8,32), 256, 0, stream>>>(Hb, w2T, b2, nullptr, nullptr,
                                          out, nullptr, nullptr, nullptr, X1f, nullptr,
                                          nullptr, nullptr, 1024, 4096, 0, 0);
}